// Round 8
// baseline (33043.149 us; speedup 1.0000x reference)
//
#include <hip/hip_runtime.h>

#define B 128
#define C 32
#define HH 16
#define V 4096
#define TB 64
#define MARGIN 5e-4f

// ---------------- helpers ----------------

__device__ __forceinline__ float cubicw(float t) {
    float at = fabsf(t);
    float at2 = at * at, at3 = at2 * at;
    if (at <= 1.f) return 1.25f * at3 - 2.25f * at2 + 1.f;
    if (at < 2.f)  return -0.75f * at3 + 3.75f * at2 - 6.f * at + 3.f;
    return 0.f;
}

// ---------------- kernels ----------------

__global__ void init_kernel(const float* __restrict__ feat, float* __restrict__ f_rest,
                            float* __restrict__ f_hat) {
    int i = blockIdx.x * 256 + threadIdx.x;
    if (i < B * C * HH * HH) { f_rest[i] = feat[i]; f_hat[i] = 0.f; }
}

__global__ void c2_kernel(const float* __restrict__ cb, double* __restrict__ c2d,
                          float* __restrict__ c2f) {
    int v = blockIdx.x * 256 + threadIdx.x;
    if (v < V) {
        const float* p = cb + v * C;
        double s = 0.0;
        #pragma unroll
        for (int j = 0; j < C; ++j) { double d = (double)p[j]; s = fma(d, d, s); }
        c2d[v] = s;
        c2f[v] = (float)s;
    }
}

// area downsample for stage-0 z only (pn=1)
__global__ void area_down_kernel(const float* __restrict__ src, float* __restrict__ dst, int pn) {
    int i = blockIdx.x * blockDim.x + threadIdx.x;
    int npx = pn * pn;
    int total = B * C * npx;
    if (i >= total) return;
    int x = i % pn, y = (i / pn) % pn, bc = i / npx;
    int sh = (y * HH) / pn, eh = ((y + 1) * HH + pn - 1) / pn;
    int sw = (x * HH) / pn, ew = ((x + 1) * HH + pn - 1) / pn;
    const float* p = src + bc * (HH * HH);
    float s = 0.f;
    for (int yy = sh; yy < eh; ++yy)
        for (int xx = sw; xx < ew; ++xx) s += p[yy * HH + xx];
    dst[i] = s * (1.f / (float)((eh - sh) * (ew - sw)));
}

// ---- GEMM-tiled fp32 top-2 scan ----
// block = 64 tokens x (V/nseg) codes, tiles of 64 codes.
// thread (cg,tg) owns 4 tokens x 4 codes; acc[4][4] in registers; z and code
// tiles both in LDS (no big per-thread arrays -> clean regalloc; R7 lesson).
__global__ __launch_bounds__(256, 4) void scan_gemm_kernel(
    const float* __restrict__ z, const float* __restrict__ cb,
    const float* __restrict__ c2f, float* __restrict__ pb1,
    float* __restrict__ pb2, int* __restrict__ pi1,
    int npx, int nseg, int nblk_tok)
{
    int total = B * npx;
    int tid = threadIdx.x;
    int tb  = blockIdx.x % nblk_tok;
    int seg = blockIdx.x / nblk_tok;
    int cps = V / nseg;
    int sb  = seg * cps;
    int t0  = tb * TB;

    __shared__ float ldsZ[C][TB + 4];
    __shared__ float ldsC[C][TB + 4];
    __shared__ float lc2[TB];
    __shared__ float mb1[16][TB + 4];
    __shared__ float mb2[16][TB + 4];
    __shared__ int   mi1[16][TB + 4];

    // stage z tile [32][64]: e -> (c = e/64, t = e%64); coalesced reads, conflict-free writes
    #pragma unroll
    for (int i = 0; i < 8; ++i) {
        int e = tid + i * 256;
        int c = e >> 6, t = e & 63;
        int tok = t0 + t;
        int bq = tok / npx, n = tok - bq * npx;
        ldsZ[c][t] = z[(bq * C + c) * npx + n];
    }

    int cg = tid & 15, tg = tid >> 4;

    float b1[4], b2[4]; int i1[4];
    #pragma unroll
    for (int i = 0; i < 4; ++i) { b1[i] = 3e38f; b2[i] = 3e38f; i1[i] = 0; }

    for (int tile = 0; tile < cps / TB; ++tile) {
        int code0 = sb + tile * TB;
        __syncthreads();
        // stage code tile transposed: thread -> code cc = tid/4, k-span (tid%4)*8
        {
            int cc = tid >> 2, k0 = (tid & 3) * 8;
            const float* cp = cb + (size_t)(code0 + cc) * C + k0;
            float4 a = *reinterpret_cast<const float4*>(cp);
            float4 bv = *reinterpret_cast<const float4*>(cp + 4);
            ldsC[k0 + 0][cc] = a.x;  ldsC[k0 + 1][cc] = a.y;
            ldsC[k0 + 2][cc] = a.z;  ldsC[k0 + 3][cc] = a.w;
            ldsC[k0 + 4][cc] = bv.x; ldsC[k0 + 5][cc] = bv.y;
            ldsC[k0 + 6][cc] = bv.z; ldsC[k0 + 7][cc] = bv.w;
            if (tid < TB) lc2[tid] = c2f[code0 + tid];
        }
        __syncthreads();

        float acc[4][4];
        #pragma unroll
        for (int i = 0; i < 4; ++i)
            #pragma unroll
            for (int j = 0; j < 4; ++j) acc[i][j] = 0.f;

        #pragma unroll
        for (int k = 0; k < C; ++k) {
            float4 zv = *reinterpret_cast<const float4*>(&ldsZ[k][tg * 4]);
            float4 cv = *reinterpret_cast<const float4*>(&ldsC[k][cg * 4]);
            acc[0][0] = fmaf(zv.x, cv.x, acc[0][0]);
            acc[0][1] = fmaf(zv.x, cv.y, acc[0][1]);
            acc[0][2] = fmaf(zv.x, cv.z, acc[0][2]);
            acc[0][3] = fmaf(zv.x, cv.w, acc[0][3]);
            acc[1][0] = fmaf(zv.y, cv.x, acc[1][0]);
            acc[1][1] = fmaf(zv.y, cv.y, acc[1][1]);
            acc[1][2] = fmaf(zv.y, cv.z, acc[1][2]);
            acc[1][3] = fmaf(zv.y, cv.w, acc[1][3]);
            acc[2][0] = fmaf(zv.z, cv.x, acc[2][0]);
            acc[2][1] = fmaf(zv.z, cv.y, acc[2][1]);
            acc[2][2] = fmaf(zv.z, cv.z, acc[2][2]);
            acc[2][3] = fmaf(zv.z, cv.w, acc[2][3]);
            acc[3][0] = fmaf(zv.w, cv.x, acc[3][0]);
            acc[3][1] = fmaf(zv.w, cv.y, acc[3][1]);
            acc[3][2] = fmaf(zv.w, cv.z, acc[3][2]);
            acc[3][3] = fmaf(zv.w, cv.w, acc[3][3]);
        }

        #pragma unroll
        for (int j = 0; j < 4; ++j) {
            int code = code0 + cg * 4 + j;
            float cc2 = lc2[cg * 4 + j];
            #pragma unroll
            for (int i = 0; i < 4; ++i) {
                float s = fmaf(-2.f, acc[i][j], cc2);
                if (s < b1[i]) { b2[i] = b1[i]; b1[i] = s; i1[i] = code; }
                else if (s < b2[i]) { b2[i] = s; }
            }
        }
    }

    // merge top-2 across the 16 code-owning threads per token
    #pragma unroll
    for (int i = 0; i < 4; ++i) {
        mb1[cg][tg * 4 + i] = b1[i];
        mb2[cg][tg * 4 + i] = b2[i];
        mi1[cg][tg * 4 + i] = i1[i];
    }
    __syncthreads();
    if (tid < TB) {
        float gb1 = 3e38f, gb2 = 3e38f; int gi1 = 0;
        #pragma unroll
        for (int g = 0; g < 16; ++g) {
            float v1 = mb1[g][tid]; int ix = mi1[g][tid];
            if (v1 < gb1 || (v1 == gb1 && ix < gi1)) { gb2 = gb1; gb1 = v1; gi1 = ix; }
            else if (v1 < gb2) { gb2 = v1; }
            float v2 = mb2[g][tid];
            if (v2 < gb2) gb2 = v2;
        }
        int tok = t0 + tid;
        int TP = nblk_tok * TB;
        pb1[(size_t)seg * TP + tok] = gb1;
        pb2[(size_t)seg * TP + tok] = gb2;
        pi1[(size_t)seg * TP + tok] = gi1;
    }
}

// merge per-seg top-2; unambiguous -> fp32 winner; ambiguous -> exact fp64 rescan
__global__ __launch_bounds__(256) void resolve_recheck_kernel(
    const float* __restrict__ pb1, const float* __restrict__ pb2,
    const int* __restrict__ pi1, const float* __restrict__ z,
    const float* __restrict__ cb, const double* __restrict__ c2d,
    int* __restrict__ idxf, int npx, int nseg, int TP)
{
    int total = B * npx;
    int tid = threadIdx.x;
    int tok = blockIdx.x * 256 + tid;

    __shared__ int flist[256];
    __shared__ int fcnt;
    if (tid == 0) fcnt = 0;
    __syncthreads();

    if (tok < total) {
        float gb1 = 3e38f, gb2 = 3e38f; int gi1 = 0;
        for (int s = 0; s < nseg; ++s) {
            float v1 = pb1[(size_t)s * TP + tok];
            if (v1 < gb1) { gb2 = gb1; gb1 = v1; gi1 = pi1[(size_t)s * TP + tok]; }
            else if (v1 < gb2) { gb2 = v1; }
            float v2 = pb2[(size_t)s * TP + tok];
            if (v2 < gb2) gb2 = v2;
        }
        if (gb2 - gb1 >= MARGIN) {
            idxf[tok] = gi1;
        } else {
            int slot = atomicAdd(&fcnt, 1);
            flist[slot] = tok;
        }
    }
    __syncthreads();
    int nf = fcnt;
    if (nf == 0) return;

    __shared__ double zsd[C];
    __shared__ double sred[256];
    __shared__ int sidx[256];

    for (int f = 0; f < nf; ++f) {
        int t2 = flist[f];
        int bb = t2 / npx, n = t2 - bb * npx;
        if (tid < C) zsd[tid] = (double)z[(bb * C + tid) * npx + n];
        __syncthreads();
        double best = 1e300; int bi = 0x7fffffff;
        for (int k = 0; k < V / 256; ++k) {
            int v = tid + k * 256;
            const float4* cp = reinterpret_cast<const float4*>(cb + (size_t)v * C);
            double acc = 0.0;
            #pragma unroll
            for (int qq = 0; qq < 8; ++qq) {
                float4 fv = cp[qq];
                acc = fma((double)fv.x, zsd[4 * qq + 0], acc);
                acc = fma((double)fv.y, zsd[4 * qq + 1], acc);
                acc = fma((double)fv.z, zsd[4 * qq + 2], acc);
                acc = fma((double)fv.w, zsd[4 * qq + 3], acc);
            }
            double s = fma(-2.0, acc, c2d[v]);
            if (s < best || (s == best && v < bi)) { best = s; bi = v; }
        }
        sred[tid] = best; sidx[tid] = bi;
        __syncthreads();
        for (int st = 128; st > 0; st >>= 1) {
            if (tid < st) {
                double o = sred[tid + st]; int oi = sidx[tid + st];
                double me = sred[tid];     int mi = sidx[tid];
                if (o < me || (o == me && oi < mi)) { sred[tid] = o; sidx[tid] = oi; }
            }
            __syncthreads();
        }
        if (tid == 0) idxf[t2] = sidx[0];
        __syncthreads();
    }
}

// fused stage tail: gather -> bicubic up -> conv3x3 -> blend/update -> context pool -> next-z pool
__global__ __launch_bounds__(256) void stage_tail_kernel(
    const int* __restrict__ idxf, const float* __restrict__ cb,
    const float* __restrict__ w, const float* __restrict__ bias,
    float* __restrict__ f_hat, float* __restrict__ f_rest,
    float* __restrict__ out, float* __restrict__ znext,
    int pn, int off, int pn2)
{
    int bb = blockIdx.x >> 1;
    int og = (blockIdx.x & 1) * 16;
    int tid = threadIdx.x;
    int npx = pn * pn;

    __shared__ float h_s[32][257];
    __shared__ float hu_s[32][257];
    float (*fh_s)[257] = &h_s[0];
    float (*fr_s)[257] = &h_s[16];

    for (int e = tid; e < 32 * npx; e += 256) {
        int c = e & 31, n = e >> 5;
        h_s[c][n] = cb[idxf[bb * npx + n] * 32 + c];
    }
    __syncthreads();

    int p = tid >> 4, q = tid & 15;
    {
        float scale = (float)pn * (1.f / 16.f);
        float srcp = (p + 0.5f) * scale - 0.5f;
        float srcq = (q + 0.5f) * scale - 0.5f;
        int fp_ = (int)floorf(srcp), fq_ = (int)floorf(srcq);
        float tp = srcp - (float)fp_, tq = srcq - (float)fq_;
        float wp[4], wq[4];
        int ip[4], iq[4];
        #pragma unroll
        for (int k = 0; k < 4; ++k) {
            wp[k] = cubicw((float)(k - 1) - tp);
            wq[k] = cubicw((float)(k - 1) - tq);
            ip[k] = min(max(fp_ + k - 1, 0), pn - 1);
            iq[k] = min(max(fq_ + k - 1, 0), pn - 1);
        }
        for (int i = 0; i < 32; ++i) {
            float s = 0.f;
            #pragma unroll
            for (int kp = 0; kp < 4; ++kp) {
                float sr = 0.f;
                #pragma unroll
                for (int kq = 0; kq < 4; ++kq)
                    sr = fmaf(wq[kq], h_s[i][ip[kp] * pn + iq[kq]], sr);
                s = fmaf(wp[kp], sr, s);
            }
            hu_s[i][tid] = s;
        }
    }
    __syncthreads();

    float acc[16];
    #pragma unroll
    for (int o = 0; o < 16; ++o) acc[o] = bias[og + o];
    for (int i = 0; i < 32; ++i) {
        float v[9];
        #pragma unroll
        for (int dy = 0; dy < 3; ++dy)
            #pragma unroll
            for (int dx = 0; dx < 3; ++dx) {
                int pp = p + dy - 1, qq = q + dx - 1;
                bool in = (pp >= 0) & (pp < 16) & (qq >= 0) & (qq < 16);
                v[dy * 3 + dx] = in ? hu_s[i][pp * 16 + qq] : 0.f;
            }
        #pragma unroll
        for (int o = 0; o < 16; ++o) {
            const float* wp_ = w + ((og + o) * 32 + i) * 9;
            #pragma unroll
            for (int k = 0; k < 9; ++k) acc[o] = fmaf(wp_[k], v[k], acc[o]);
        }
    }

    #pragma unroll
    for (int o = 0; o < 16; ++o) {
        int gi = (bb * 32 + og + o) * 256 + tid;
        float hu = hu_s[og + o][tid];
        float blend = 0.5f * hu + 0.5f * acc[o];
        float nf = f_hat[gi] + blend;
        float nr = f_rest[gi] - blend;
        f_hat[gi] = nf; f_rest[gi] = nr;
        fh_s[o][tid] = nf; fr_s[o][tid] = nr;
    }
    __syncthreads();

    for (int e = tid; e < 16 * npx; e += 256) {
        int o = e & 15, n = e >> 4;
        int y = n / pn, x = n - y * pn;
        int sh = (y * HH) / pn, eh = ((y + 1) * HH + pn - 1) / pn;
        int sw = (x * HH) / pn, ew = ((x + 1) * HH + pn - 1) / pn;
        float s = 0.f;
        for (int yy = sh; yy < eh; ++yy)
            for (int xx = sw; xx < ew; ++xx) s += fh_s[o][yy * 16 + xx];
        out[((bb * 680) + off + n) * 32 + og + o] = s * (1.f / (float)((eh - sh) * (ew - sw)));
    }

    if (pn2 > 0) {
        int npx2 = pn2 * pn2;
        for (int e = tid; e < 16 * npx2; e += 256) {
            int o = e / npx2, n = e - o * npx2;
            int y = n / pn2, x = n - y * pn2;
            int sh = (y * HH) / pn2, eh = ((y + 1) * HH + pn2 - 1) / pn2;
            int sw = (x * HH) / pn2, ew = ((x + 1) * HH + pn2 - 1) / pn2;
            float s = 0.f;
            for (int yy = sh; yy < eh; ++yy)
                for (int xx = sw; xx < ew; ++xx) s += fr_s[o][yy * 16 + xx];
            znext[(bb * 32 + og + o) * npx2 + n] = s * (1.f / (float)((eh - sh) * (ew - sw)));
        }
    }
}

// ---------------- launch ----------------

extern "C" void kernel_launch(void* const* d_in, const int* in_sizes, int n_in,
                              void* d_out, int out_size, void* d_ws, size_t ws_size,
                              hipStream_t stream) {
    const float* feat = (const float*)d_in[0];
    const float* cb   = (const float*)d_in[1];
    const float* phiw = (const float*)d_in[2];
    const float* phib = (const float*)d_in[3];
    float* out = (float*)d_out;
    float* wsf = (float*)d_ws;

    const int NE = B * C * HH * HH; // 1048576
    float* f_rest = wsf;
    float* f_hat  = wsf + NE;
    float* zbuf   = wsf + 2 * NE;
    char*  tail   = (char*)(wsf + 3 * NE);
    double* c2d = (double*)tail;                        // 32 KB
    float*  c2f = (float*)(tail + (32 << 10));          // 16 KB
    float*  pb1 = (float*)(tail + (48 << 10));          // 3 MB
    float*  pb2 = (float*)(tail + (48 << 10) + 3145728);
    int*    pi1 = (int*)  (tail + (48 << 10) + 2 * 3145728);
    int*    idxf = (int*) (tail + (48 << 10) + 3 * 3145728); // 128 KB

    static const int PN_[10]   = {1, 2, 3, 4, 5, 6, 8, 10, 13, 16};
    static const int PI_[10]   = {0, 0, 1, 1, 1, 2, 2, 2, 3, 3};
    static const int OFF_[10]  = {0, 1, 5, 14, 30, 55, 91, 155, 255, 424};
    static const int NSEG_[10] = {64, 32, 16, 16, 8, 8, 4, 2, 2, 2};

    init_kernel<<<dim3((NE + 255) / 256), dim3(256), 0, stream>>>(feat, f_rest, f_hat);
    c2_kernel<<<dim3(V / 256), dim3(256), 0, stream>>>(cb, c2d, c2f);
    area_down_kernel<<<dim3((B * C + 255) / 256), dim3(256), 0, stream>>>(f_rest, zbuf, 1);

    for (int si = 0; si < 10; ++si) {
        int pn = PN_[si], npx = pn * pn;
        int tokens = B * npx;          // always divisible by 64
        int nseg = NSEG_[si];
        int nblk_tok = tokens / TB;

        scan_gemm_kernel<<<dim3(nblk_tok * nseg), dim3(256), 0, stream>>>(
            zbuf, cb, c2f, pb1, pb2, pi1, npx, nseg, nblk_tok);

        resolve_recheck_kernel<<<dim3((tokens + 255) / 256), dim3(256), 0, stream>>>(
            pb1, pb2, pi1, zbuf, cb, c2d, idxf, npx, nseg, tokens);

        int pn2 = (si < 9) ? PN_[si + 1] : 0;
        stage_tail_kernel<<<dim3(B * 2), dim3(256), 0, stream>>>(
            idxf, cb, phiw + PI_[si] * C * C * 9, phib + PI_[si] * C,
            f_hat, f_rest, out, zbuf, pn, OFF_[si], pn2);
    }
}

// Round 9
// 1222.157 us; speedup vs baseline: 27.0367x; 27.0367x over previous
//
#include <hip/hip_runtime.h>

#define B 128
#define C 32
#define HH 16
#define V 4096
#define TB 64
#define MARGIN 5e-4f

// ---------------- helpers ----------------

__device__ __forceinline__ float cubicw(float t) {
    float at = fabsf(t);
    float at2 = at * at, at3 = at2 * at;
    if (at <= 1.f) return 1.25f * at3 - 2.25f * at2 + 1.f;
    if (at < 2.f)  return -0.75f * at3 + 3.75f * at2 - 6.f * at + 3.f;
    return 0.f;
}

// ---------------- kernels ----------------

__global__ void init_kernel(const float* __restrict__ feat, float* __restrict__ f_rest,
                            float* __restrict__ f_hat) {
    int i = blockIdx.x * 256 + threadIdx.x;
    if (i < B * C * HH * HH) { f_rest[i] = feat[i]; f_hat[i] = 0.f; }
}

__global__ void c2_kernel(const float* __restrict__ cb, double* __restrict__ c2d,
                          float* __restrict__ c2f) {
    int v = blockIdx.x * 256 + threadIdx.x;
    if (v < V) {
        const float* p = cb + v * C;
        double s = 0.0;
        #pragma unroll
        for (int j = 0; j < C; ++j) { double d = (double)p[j]; s = fma(d, d, s); }
        c2d[v] = s;
        c2f[v] = (float)s;
    }
}

// area downsample for stage-0 z only (pn=1)
__global__ void area_down_kernel(const float* __restrict__ src, float* __restrict__ dst, int pn) {
    int i = blockIdx.x * blockDim.x + threadIdx.x;
    int npx = pn * pn;
    int total = B * C * npx;
    if (i >= total) return;
    int x = i % pn, y = (i / pn) % pn, bc = i / npx;
    int sh = (y * HH) / pn, eh = ((y + 1) * HH + pn - 1) / pn;
    int sw = (x * HH) / pn, ew = ((x + 1) * HH + pn - 1) / pn;
    const float* p = src + bc * (HH * HH);
    float s = 0.f;
    for (int yy = sh; yy < eh; ++yy)
        for (int xx = sw; xx < ew; ++xx) s += p[yy * HH + xx];
    dst[i] = s * (1.f / (float)((eh - sh) * (ew - sw)));
}

// ---- GEMM-tiled fp32 top-2 scan ----
// block = 64 tokens x (V/nseg) codes, tiles of 64 codes; thread owns 4x4.
// k-loop unroll LIMITED to 4: full unroll let the scheduler hoist all 64
// ds_reads, blowing registers and spilling acc to scratch (R8: 45 GB traffic).
__global__ __launch_bounds__(256, 4) void scan_gemm_kernel(
    const float* __restrict__ z, const float* __restrict__ cb,
    const float* __restrict__ c2f, float* __restrict__ pb1,
    float* __restrict__ pb2, int* __restrict__ pi1,
    int npx, int nseg, int nblk_tok)
{
    int tid = threadIdx.x;
    int tb  = blockIdx.x % nblk_tok;
    int seg = blockIdx.x / nblk_tok;
    int cps = V / nseg;
    int sb  = seg * cps;
    int t0  = tb * TB;

    __shared__ float ldsZ[C][TB + 4];
    __shared__ float ldsC[C][TB + 4];
    __shared__ float lc2[TB];
    __shared__ float mb1[16][TB + 4];
    __shared__ float mb2[16][TB + 4];
    __shared__ int   mi1[16][TB + 4];

    // stage z tile [32][64]: coalesced reads, conflict-free writes
    #pragma unroll
    for (int i = 0; i < 8; ++i) {
        int e = tid + i * 256;
        int c = e >> 6, t = e & 63;
        int tok = t0 + t;
        int bq = tok / npx, n = tok - bq * npx;
        ldsZ[c][t] = z[(bq * C + c) * npx + n];
    }

    int cg = tid & 15, tg = tid >> 4;

    float b1[4], b2[4]; int i1[4];
    #pragma unroll
    for (int i = 0; i < 4; ++i) { b1[i] = 3e38f; b2[i] = 3e38f; i1[i] = 0; }

    for (int tile = 0; tile < cps / TB; ++tile) {
        int code0 = sb + tile * TB;
        __syncthreads();
        // stage code tile transposed; cc = tid&63 -> wave writes 64 distinct cc
        // -> bank (4k+cc)%32, 2 lanes/bank (free). R8's (cc=tid>>2) was 4-way.
        {
            int cc = tid & 63, k0 = (tid >> 6) * 8;
            const float* cp = cb + (size_t)(code0 + cc) * C + k0;
            float4 a = *reinterpret_cast<const float4*>(cp);
            float4 bv = *reinterpret_cast<const float4*>(cp + 4);
            ldsC[k0 + 0][cc] = a.x;  ldsC[k0 + 1][cc] = a.y;
            ldsC[k0 + 2][cc] = a.z;  ldsC[k0 + 3][cc] = a.w;
            ldsC[k0 + 4][cc] = bv.x; ldsC[k0 + 5][cc] = bv.y;
            ldsC[k0 + 6][cc] = bv.z; ldsC[k0 + 7][cc] = bv.w;
            if (tid < TB) lc2[tid] = c2f[code0 + tid];
        }
        __syncthreads();

        float acc[4][4];
        #pragma unroll
        for (int i = 0; i < 4; ++i)
            #pragma unroll
            for (int j = 0; j < 4; ++j) acc[i][j] = 0.f;

        #pragma unroll 4
        for (int k = 0; k < C; ++k) {
            float4 zv = *reinterpret_cast<const float4*>(&ldsZ[k][tg * 4]);
            float4 cv = *reinterpret_cast<const float4*>(&ldsC[k][cg * 4]);
            acc[0][0] = fmaf(zv.x, cv.x, acc[0][0]);
            acc[0][1] = fmaf(zv.x, cv.y, acc[0][1]);
            acc[0][2] = fmaf(zv.x, cv.z, acc[0][2]);
            acc[0][3] = fmaf(zv.x, cv.w, acc[0][3]);
            acc[1][0] = fmaf(zv.y, cv.x, acc[1][0]);
            acc[1][1] = fmaf(zv.y, cv.y, acc[1][1]);
            acc[1][2] = fmaf(zv.y, cv.z, acc[1][2]);
            acc[1][3] = fmaf(zv.y, cv.w, acc[1][3]);
            acc[2][0] = fmaf(zv.z, cv.x, acc[2][0]);
            acc[2][1] = fmaf(zv.z, cv.y, acc[2][1]);
            acc[2][2] = fmaf(zv.z, cv.z, acc[2][2]);
            acc[2][3] = fmaf(zv.z, cv.w, acc[2][3]);
            acc[3][0] = fmaf(zv.w, cv.x, acc[3][0]);
            acc[3][1] = fmaf(zv.w, cv.y, acc[3][1]);
            acc[3][2] = fmaf(zv.w, cv.z, acc[3][2]);
            acc[3][3] = fmaf(zv.w, cv.w, acc[3][3]);
        }

        #pragma unroll
        for (int j = 0; j < 4; ++j) {
            int code = code0 + cg * 4 + j;
            float cc2 = lc2[cg * 4 + j];
            #pragma unroll
            for (int i = 0; i < 4; ++i) {
                float s = fmaf(-2.f, acc[i][j], cc2);
                if (s < b1[i]) { b2[i] = b1[i]; b1[i] = s; i1[i] = code; }
                else if (s < b2[i]) { b2[i] = s; }
            }
        }
    }

    // merge top-2 across the 16 code-owning threads per token
    #pragma unroll
    for (int i = 0; i < 4; ++i) {
        mb1[cg][tg * 4 + i] = b1[i];
        mb2[cg][tg * 4 + i] = b2[i];
        mi1[cg][tg * 4 + i] = i1[i];
    }
    __syncthreads();
    if (tid < TB) {
        float gb1 = 3e38f, gb2 = 3e38f; int gi1 = 0;
        #pragma unroll
        for (int g = 0; g < 16; ++g) {
            float v1 = mb1[g][tid]; int ix = mi1[g][tid];
            if (v1 < gb1 || (v1 == gb1 && ix < gi1)) { gb2 = gb1; gb1 = v1; gi1 = ix; }
            else if (v1 < gb2) { gb2 = v1; }
            float v2 = mb2[g][tid];
            if (v2 < gb2) gb2 = v2;
        }
        int tok = t0 + tid;
        int TP = nblk_tok * TB;   // == total tokens
        pb1[(size_t)seg * TP + tok] = gb1;
        pb2[(size_t)seg * TP + tok] = gb2;
        pi1[(size_t)seg * TP + tok] = gi1;
    }
}

// fused stage tail: combine+recheck -> gather -> bicubic -> conv3x3 -> blend/update
//                   -> context pool -> next-z pool
__global__ __launch_bounds__(256) void stage_tail_kernel(
    const float* __restrict__ pb1, const float* __restrict__ pb2,
    const int* __restrict__ pi1, const float* __restrict__ z,
    const float* __restrict__ cb, const double* __restrict__ c2d,
    const float* __restrict__ w, const float* __restrict__ bias,
    float* __restrict__ f_hat, float* __restrict__ f_rest,
    float* __restrict__ out, float* __restrict__ znext,
    int pn, int off, int pn2, int nseg)
{
    int bb = blockIdx.x >> 1;
    int og = (blockIdx.x & 1) * 16;
    int tid = threadIdx.x;
    int npx = pn * pn;
    int total = B * npx;

    __shared__ float h_s[32][257];
    __shared__ float hu_s[32][257];
    __shared__ int idx_s[256];
    __shared__ int flist[256];
    __shared__ int fcnt;
    __shared__ double zsd[C];
    __shared__ double sred[256];
    __shared__ int sidx[256];
    float (*fh_s)[257] = &h_s[0];
    float (*fr_s)[257] = &h_s[16];

    // 0) combine per-segment top-2 -> idx or ambiguous flag
    if (tid == 0) fcnt = 0;
    __syncthreads();
    for (int n = tid; n < npx; n += 256) {
        int tok = bb * npx + n;
        float gb1 = 3e38f, gb2 = 3e38f; int gi1 = 0;
        for (int s = 0; s < nseg; ++s) {
            float v1 = pb1[(size_t)s * total + tok];
            if (v1 < gb1) { gb2 = gb1; gb1 = v1; gi1 = pi1[(size_t)s * total + tok]; }
            else if (v1 < gb2) { gb2 = v1; }
            float v2 = pb2[(size_t)s * total + tok];
            if (v2 < gb2) gb2 = v2;
        }
        idx_s[n] = gi1;
        if (gb2 - gb1 < MARGIN) { int slot = atomicAdd(&fcnt, 1); flist[slot] = n; }
    }
    __syncthreads();

    // 1) exact fp64 rescan for ambiguous tokens (block-parallel, rare)
    int nf = fcnt;
    for (int f = 0; f < nf; ++f) {
        int n = flist[f];
        if (tid < C) zsd[tid] = (double)z[(bb * C + tid) * npx + n];
        __syncthreads();
        double best = 1e300; int bi = 0x7fffffff;
        for (int k = 0; k < V / 256; ++k) {
            int v = tid + k * 256;
            const float4* cp = reinterpret_cast<const float4*>(cb + (size_t)v * C);
            double acc = 0.0;
            #pragma unroll
            for (int qq = 0; qq < 8; ++qq) {
                float4 fv = cp[qq];
                acc = fma((double)fv.x, zsd[4 * qq + 0], acc);
                acc = fma((double)fv.y, zsd[4 * qq + 1], acc);
                acc = fma((double)fv.z, zsd[4 * qq + 2], acc);
                acc = fma((double)fv.w, zsd[4 * qq + 3], acc);
            }
            double s = fma(-2.0, acc, c2d[v]);
            if (s < best || (s == best && v < bi)) { best = s; bi = v; }
        }
        sred[tid] = best; sidx[tid] = bi;
        __syncthreads();
        for (int st = 128; st > 0; st >>= 1) {
            if (tid < st) {
                double o = sred[tid + st]; int oi = sidx[tid + st];
                double me = sred[tid];     int mi = sidx[tid];
                if (o < me || (o == me && oi < mi)) { sred[tid] = o; sidx[tid] = oi; }
            }
            __syncthreads();
        }
        if (tid == 0) idx_s[n] = sidx[0];
        __syncthreads();
    }
    __syncthreads();

    // 2) gather hard embeddings h[c][n] = cb[idx[n]][c]
    for (int e = tid; e < 32 * npx; e += 256) {
        int c = e & 31, n = e >> 5;
        h_s[c][n] = cb[idx_s[n] * 32 + c];
    }
    __syncthreads();

    // 3) bicubic upsample pn x pn -> 16 x 16 (identity when pn==16)
    int p = tid >> 4, q = tid & 15;
    {
        float scale = (float)pn * (1.f / 16.f);
        float srcp = (p + 0.5f) * scale - 0.5f;
        float srcq = (q + 0.5f) * scale - 0.5f;
        int fp_ = (int)floorf(srcp), fq_ = (int)floorf(srcq);
        float tp = srcp - (float)fp_, tq = srcq - (float)fq_;
        float wp[4], wq[4];
        int ip[4], iq[4];
        #pragma unroll
        for (int k = 0; k < 4; ++k) {
            wp[k] = cubicw((float)(k - 1) - tp);
            wq[k] = cubicw((float)(k - 1) - tq);
            ip[k] = min(max(fp_ + k - 1, 0), pn - 1);
            iq[k] = min(max(fq_ + k - 1, 0), pn - 1);
        }
        for (int i = 0; i < 32; ++i) {
            float s = 0.f;
            #pragma unroll
            for (int kp = 0; kp < 4; ++kp) {
                float sr = 0.f;
                #pragma unroll
                for (int kq = 0; kq < 4; ++kq)
                    sr = fmaf(wq[kq], h_s[i][ip[kp] * pn + iq[kq]], sr);
                s = fmaf(wp[kp], sr, s);
            }
            hu_s[i][tid] = s;
        }
    }
    __syncthreads();

    // 4) conv 3x3 SAME over 32 in-ch for out-ch og..og+15
    float acc[16];
    #pragma unroll
    for (int o = 0; o < 16; ++o) acc[o] = bias[og + o];
    for (int i = 0; i < 32; ++i) {
        float v[9];
        #pragma unroll
        for (int dy = 0; dy < 3; ++dy)
            #pragma unroll
            for (int dx = 0; dx < 3; ++dx) {
                int pp = p + dy - 1, qq = q + dx - 1;
                bool in = (pp >= 0) & (pp < 16) & (qq >= 0) & (qq < 16);
                v[dy * 3 + dx] = in ? hu_s[i][pp * 16 + qq] : 0.f;
            }
        #pragma unroll
        for (int o = 0; o < 16; ++o) {
            const float* wp_ = w + ((og + o) * 32 + i) * 9;
            #pragma unroll
            for (int k = 0; k < 9; ++k) acc[o] = fmaf(wp_[k], v[k], acc[o]);
        }
    }

    // 5) blend + update f_hat/f_rest, stage new values into LDS (overlay on h_s)
    #pragma unroll
    for (int o = 0; o < 16; ++o) {
        int gi = (bb * 32 + og + o) * 256 + tid;
        float hu = hu_s[og + o][tid];
        float blend = 0.5f * hu + 0.5f * acc[o];
        float nf = f_hat[gi] + blend;
        float nr = f_rest[gi] - blend;
        f_hat[gi] = nf; f_rest[gi] = nr;
        fh_s[o][tid] = nf; fr_s[o][tid] = nr;
    }
    __syncthreads();

    // 6) context: area-pool new f_hat to pn x pn, write transposed slice of out [B,680,C]
    for (int e = tid; e < 16 * npx; e += 256) {
        int o = e & 15, n = e >> 4;
        int y = n / pn, x = n - y * pn;
        int sh = (y * HH) / pn, eh = ((y + 1) * HH + pn - 1) / pn;
        int sw = (x * HH) / pn, ew = ((x + 1) * HH + pn - 1) / pn;
        float s = 0.f;
        for (int yy = sh; yy < eh; ++yy)
            for (int xx = sw; xx < ew; ++xx) s += fh_s[o][yy * 16 + xx];
        out[((bb * 680) + off + n) * 32 + og + o] = s * (1.f / (float)((eh - sh) * (ew - sw)));
    }

    // 7) next-stage z: area-pool new f_rest to pn2 x pn2
    if (pn2 > 0) {
        int npx2 = pn2 * pn2;
        for (int e = tid; e < 16 * npx2; e += 256) {
            int o = e / npx2, n = e - o * npx2;
            int y = n / pn2, x = n - y * pn2;
            int sh = (y * HH) / pn2, eh = ((y + 1) * HH + pn2 - 1) / pn2;
            int sw = (x * HH) / pn2, ew = ((x + 1) * HH + pn2 - 1) / pn2;
            float s = 0.f;
            for (int yy = sh; yy < eh; ++yy)
                for (int xx = sw; xx < ew; ++xx) s += fr_s[o][yy * 16 + xx];
            znext[(bb * 32 + og + o) * npx2 + n] = s * (1.f / (float)((eh - sh) * (ew - sw)));
        }
    }
}

// ---------------- launch ----------------

extern "C" void kernel_launch(void* const* d_in, const int* in_sizes, int n_in,
                              void* d_out, int out_size, void* d_ws, size_t ws_size,
                              hipStream_t stream) {
    const float* feat = (const float*)d_in[0];
    const float* cb   = (const float*)d_in[1];
    const float* phiw = (const float*)d_in[2];
    const float* phib = (const float*)d_in[3];
    float* out = (float*)d_out;
    float* wsf = (float*)d_ws;

    const int NE = B * C * HH * HH; // 1048576
    float* f_rest = wsf;
    float* f_hat  = wsf + NE;
    float* zbuf   = wsf + 2 * NE;
    char*  tail   = (char*)(wsf + 3 * NE);
    double* c2d = (double*)tail;                        // 32 KB
    float*  c2f = (float*)(tail + (32 << 10));          // 16 KB
    float*  pb1 = (float*)(tail + (48 << 10));          // 3 MB each
    float*  pb2 = (float*)(tail + (48 << 10) + 3145728);
    int*    pi1 = (int*)  (tail + (48 << 10) + 2 * 3145728);

    static const int PN_[10]   = {1, 2, 3, 4, 5, 6, 8, 10, 13, 16};
    static const int PI_[10]   = {0, 0, 1, 1, 1, 2, 2, 2, 3, 3};
    static const int OFF_[10]  = {0, 1, 5, 14, 30, 55, 91, 155, 255, 424};
    static const int NSEG_[10] = {64, 64, 64, 32, 16, 16, 8, 8, 4, 4};

    init_kernel<<<dim3((NE + 255) / 256), dim3(256), 0, stream>>>(feat, f_rest, f_hat);
    c2_kernel<<<dim3(V / 256), dim3(256), 0, stream>>>(cb, c2d, c2f);
    area_down_kernel<<<dim3((B * C + 255) / 256), dim3(256), 0, stream>>>(f_rest, zbuf, 1);

    for (int si = 0; si < 10; ++si) {
        int pn = PN_[si], npx = pn * pn;
        int tokens = B * npx;          // always divisible by 64
        int nseg = NSEG_[si];
        int nblk_tok = tokens / TB;

        scan_gemm_kernel<<<dim3(nblk_tok * nseg), dim3(256), 0, stream>>>(
            zbuf, cb, c2f, pb1, pb2, pi1, npx, nseg, nblk_tok);

        int pn2 = (si < 9) ? PN_[si + 1] : 0;
        stage_tail_kernel<<<dim3(B * 2), dim3(256), 0, stream>>>(
            pb1, pb2, pi1, zbuf, cb, c2d,
            phiw + PI_[si] * C * C * 9, phib + PI_[si] * C,
            f_hat, f_rest, out, zbuf, pn, OFF_[si], pn2, nseg);
    }
}

// Round 10
// 1178.273 us; speedup vs baseline: 28.0437x; 1.0372x over previous
//
#include <hip/hip_runtime.h>

#define B 128
#define C 32
#define HH 16
#define V 4096
#define TB 64
#define CB 128
#define MARGIN 5e-4f

// ---------------- helpers ----------------

__device__ __forceinline__ float cubicw(float t) {
    float at = fabsf(t);
    float at2 = at * at, at3 = at2 * at;
    if (at <= 1.f) return 1.25f * at3 - 2.25f * at2 + 1.f;
    if (at < 2.f)  return -0.75f * at3 + 3.75f * at2 - 6.f * at + 3.f;
    return 0.f;
}

// ---------------- kernels ----------------

__global__ void init_kernel(const float* __restrict__ feat, float* __restrict__ f_rest,
                            float* __restrict__ f_hat) {
    int i = blockIdx.x * 256 + threadIdx.x;
    if (i < B * C * HH * HH) { f_rest[i] = feat[i]; f_hat[i] = 0.f; }
}

__global__ void c2_kernel(const float* __restrict__ cb, double* __restrict__ c2d,
                          float* __restrict__ c2f) {
    int v = blockIdx.x * 256 + threadIdx.x;
    if (v < V) {
        const float* p = cb + v * C;
        double s = 0.0;
        #pragma unroll
        for (int j = 0; j < C; ++j) { double d = (double)p[j]; s = fma(d, d, s); }
        c2d[v] = s;
        c2f[v] = (float)s;
    }
}

// area downsample for stage-0 z only (pn=1)
__global__ void area_down_kernel(const float* __restrict__ src, float* __restrict__ dst, int pn) {
    int i = blockIdx.x * blockDim.x + threadIdx.x;
    int npx = pn * pn;
    int total = B * C * npx;
    if (i >= total) return;
    int x = i % pn, y = (i / pn) % pn, bc = i / npx;
    int sh = (y * HH) / pn, eh = ((y + 1) * HH + pn - 1) / pn;
    int sw = (x * HH) / pn, ew = ((x + 1) * HH + pn - 1) / pn;
    const float* p = src + bc * (HH * HH);
    float s = 0.f;
    for (int yy = sh; yy < eh; ++yy)
        for (int xx = sw; xx < ew; ++xx) s += p[yy * HH + xx];
    dst[i] = s * (1.f / (float)((eh - sh) * (ew - sw)));
}

// ---- GEMM-tiled fp32 top-2 scan, 64 tok x 128 code tiles, thread = 4 tok x 8 codes ----
// 3 ds_read_b128 feed 32 FMA (2x better LDS:FMA than R9); cv reads at 16B stride
// (2-way, free); unroll 2 keeps the register window under the R8 spill cliff.
__global__ __launch_bounds__(256, 4) void scan_gemm_kernel(
    const float* __restrict__ z, const float* __restrict__ cb,
    const float* __restrict__ c2f, float* __restrict__ pb1,
    float* __restrict__ pb2, int* __restrict__ pi1,
    int npx, int nseg, int nblk_tok)
{
    int tid = threadIdx.x;
    int tb  = blockIdx.x % nblk_tok;
    int seg = blockIdx.x / nblk_tok;
    int cps = V / nseg;           // >= 128 always
    int sb  = seg * cps;
    int t0  = tb * TB;
    int total = B * npx;

    __shared__ float ldsZ[C][TB + 4];
    __shared__ float ldsC[C][CB + 4];
    __shared__ float lc2[CB];
    // merge arrays overlay ldsC (dead after the last tile)
    float* mb1 = &ldsC[0][0];            // [16][68]
    float* mb2 = mb1 + 16 * 68;
    int*   mi1 = (int*)(mb2 + 16 * 68);

    // stage z tile [32][64]
    #pragma unroll
    for (int i = 0; i < 8; ++i) {
        int e = tid + i * 256;
        int c = e >> 6, t = e & 63;
        int tok = t0 + t;
        int bq = tok / npx, n = tok - bq * npx;
        ldsZ[c][t] = z[(bq * C + c) * npx + n];
    }

    int cg = tid & 15, tg = tid >> 4;

    float b1[4], b2[4]; int i1[4];
    #pragma unroll
    for (int i = 0; i < 4; ++i) { b1[i] = 3e38f; b2[i] = 3e38f; i1[i] = 0; }

    for (int tile = 0; tile < cps / CB; ++tile) {
        int code0 = sb + tile * CB;
        __syncthreads();
        // stage 128-code tile transposed: cc = tid&127, k-half = tid>>7
        {
            int cc = tid & 127, k0 = (tid >> 7) * 16;
            const float4* cp = reinterpret_cast<const float4*>(cb + (size_t)(code0 + cc) * C + k0);
            float4 q0 = cp[0], q1 = cp[1], q2 = cp[2], q3 = cp[3];
            ldsC[k0 +  0][cc] = q0.x; ldsC[k0 +  1][cc] = q0.y;
            ldsC[k0 +  2][cc] = q0.z; ldsC[k0 +  3][cc] = q0.w;
            ldsC[k0 +  4][cc] = q1.x; ldsC[k0 +  5][cc] = q1.y;
            ldsC[k0 +  6][cc] = q1.z; ldsC[k0 +  7][cc] = q1.w;
            ldsC[k0 +  8][cc] = q2.x; ldsC[k0 +  9][cc] = q2.y;
            ldsC[k0 + 10][cc] = q2.z; ldsC[k0 + 11][cc] = q2.w;
            ldsC[k0 + 12][cc] = q3.x; ldsC[k0 + 13][cc] = q3.y;
            ldsC[k0 + 14][cc] = q3.z; ldsC[k0 + 15][cc] = q3.w;
            if (tid < CB) lc2[tid] = c2f[code0 + tid];
        }
        __syncthreads();

        float acc[4][8];
        #pragma unroll
        for (int i = 0; i < 4; ++i)
            #pragma unroll
            for (int j = 0; j < 8; ++j) acc[i][j] = 0.f;

        #pragma unroll 2
        for (int k = 0; k < C; ++k) {
            float4 zv = *reinterpret_cast<const float4*>(&ldsZ[k][tg * 4]);
            float4 c0 = *reinterpret_cast<const float4*>(&ldsC[k][cg * 4]);
            float4 c1 = *reinterpret_cast<const float4*>(&ldsC[k][64 + cg * 4]);
#define FMA8(i, zc) \
            acc[i][0] = fmaf(zc, c0.x, acc[i][0]); acc[i][1] = fmaf(zc, c0.y, acc[i][1]); \
            acc[i][2] = fmaf(zc, c0.z, acc[i][2]); acc[i][3] = fmaf(zc, c0.w, acc[i][3]); \
            acc[i][4] = fmaf(zc, c1.x, acc[i][4]); acc[i][5] = fmaf(zc, c1.y, acc[i][5]); \
            acc[i][6] = fmaf(zc, c1.z, acc[i][6]); acc[i][7] = fmaf(zc, c1.w, acc[i][7]);
            FMA8(0, zv.x) FMA8(1, zv.y) FMA8(2, zv.z) FMA8(3, zv.w)
#undef FMA8
        }

        // top-2 epilogue; ascending code order within thread (half 0 then 1) for ties
        #pragma unroll
        for (int h = 0; h < 2; ++h)
            #pragma unroll
            for (int j = 0; j < 4; ++j) {
                int col = h * 64 + cg * 4 + j;
                int code = code0 + col;
                float cc2 = lc2[col];
                #pragma unroll
                for (int i = 0; i < 4; ++i) {
                    float s = fmaf(-2.f, acc[i][h * 4 + j], cc2);
                    if (s < b1[i]) { b2[i] = b1[i]; b1[i] = s; i1[i] = code; }
                    else if (s < b2[i]) { b2[i] = s; }
                }
            }
    }

    __syncthreads();   // ldsC dead -> merge overlay
    #pragma unroll
    for (int i = 0; i < 4; ++i) {
        mb1[cg * 68 + tg * 4 + i] = b1[i];
        mb2[cg * 68 + tg * 4 + i] = b2[i];
        mi1[cg * 68 + tg * 4 + i] = i1[i];
    }
    __syncthreads();
    if (tid < TB) {
        float gb1 = 3e38f, gb2 = 3e38f; int gi1 = 0;
        #pragma unroll
        for (int g = 0; g < 16; ++g) {
            float v1 = mb1[g * 68 + tid]; int ix = mi1[g * 68 + tid];
            if (v1 < gb1 || (v1 == gb1 && ix < gi1)) { gb2 = gb1; gb1 = v1; gi1 = ix; }
            else if (v1 < gb2) { gb2 = v1; }
            float v2 = mb2[g * 68 + tid];
            if (v2 < gb2) gb2 = v2;
        }
        int tok = t0 + tid;
        pb1[(size_t)seg * total + tok] = gb1;
        pb2[(size_t)seg * total + tok] = gb2;
        pi1[(size_t)seg * total + tok] = gi1;
    }
}

// fused stage tail: combine+recheck -> gather -> bicubic -> conv3x3 -> blend/update
//                   -> context pool -> next-z pool
__global__ __launch_bounds__(256) void stage_tail_kernel(
    const float* __restrict__ pb1, const float* __restrict__ pb2,
    const int* __restrict__ pi1, const float* __restrict__ z,
    const float* __restrict__ cb, const double* __restrict__ c2d,
    const float* __restrict__ w, const float* __restrict__ bias,
    float* __restrict__ f_hat, float* __restrict__ f_rest,
    float* __restrict__ out, float* __restrict__ znext,
    int pn, int off, int pn2, int nseg)
{
    int bb = blockIdx.x >> 1;
    int og = (blockIdx.x & 1) * 16;
    int tid = threadIdx.x;
    int npx = pn * pn;
    int total = B * npx;

    __shared__ float h_s[32][257];
    __shared__ float hu_s[32][257];
    __shared__ int idx_s[256];
    __shared__ int flist[256];
    __shared__ int fcnt;
    __shared__ double zsd[C];
    __shared__ double sred[256];
    __shared__ int sidx[256];
    float (*fh_s)[257] = &h_s[0];
    float (*fr_s)[257] = &h_s[16];

    // 0) combine per-segment top-2 -> idx or ambiguous flag
    if (tid == 0) fcnt = 0;
    __syncthreads();
    for (int n = tid; n < npx; n += 256) {
        int tok = bb * npx + n;
        float gb1 = 3e38f, gb2 = 3e38f; int gi1 = 0;
        for (int s = 0; s < nseg; ++s) {
            float v1 = pb1[(size_t)s * total + tok];
            if (v1 < gb1) { gb2 = gb1; gb1 = v1; gi1 = pi1[(size_t)s * total + tok]; }
            else if (v1 < gb2) { gb2 = v1; }
            float v2 = pb2[(size_t)s * total + tok];
            if (v2 < gb2) gb2 = v2;
        }
        idx_s[n] = gi1;
        if (gb2 - gb1 < MARGIN) { int slot = atomicAdd(&fcnt, 1); flist[slot] = n; }
    }
    __syncthreads();

    // 1) exact fp64 rescan for ambiguous tokens (block-parallel, rare)
    int nf = fcnt;
    for (int f = 0; f < nf; ++f) {
        int n = flist[f];
        if (tid < C) zsd[tid] = (double)z[(bb * C + tid) * npx + n];
        __syncthreads();
        double best = 1e300; int bi = 0x7fffffff;
        for (int k = 0; k < V / 256; ++k) {
            int v = tid + k * 256;
            const float4* cp = reinterpret_cast<const float4*>(cb + (size_t)v * C);
            double acc = 0.0;
            #pragma unroll
            for (int qq = 0; qq < 8; ++qq) {
                float4 fv = cp[qq];
                acc = fma((double)fv.x, zsd[4 * qq + 0], acc);
                acc = fma((double)fv.y, zsd[4 * qq + 1], acc);
                acc = fma((double)fv.z, zsd[4 * qq + 2], acc);
                acc = fma((double)fv.w, zsd[4 * qq + 3], acc);
            }
            double s = fma(-2.0, acc, c2d[v]);
            if (s < best || (s == best && v < bi)) { best = s; bi = v; }
        }
        sred[tid] = best; sidx[tid] = bi;
        __syncthreads();
        for (int st = 128; st > 0; st >>= 1) {
            if (tid < st) {
                double o = sred[tid + st]; int oi = sidx[tid + st];
                double me = sred[tid];     int mi = sidx[tid];
                if (o < me || (o == me && oi < mi)) { sred[tid] = o; sidx[tid] = oi; }
            }
            __syncthreads();
        }
        if (tid == 0) idx_s[n] = sidx[0];
        __syncthreads();
    }
    __syncthreads();

    // 2) gather hard embeddings h[c][n] = cb[idx[n]][c]
    for (int e = tid; e < 32 * npx; e += 256) {
        int c = e & 31, n = e >> 5;
        h_s[c][n] = cb[idx_s[n] * 32 + c];
    }
    __syncthreads();

    // 3) bicubic upsample pn x pn -> 16 x 16 (identity when pn==16)
    int p = tid >> 4, q = tid & 15;
    {
        float scale = (float)pn * (1.f / 16.f);
        float srcp = (p + 0.5f) * scale - 0.5f;
        float srcq = (q + 0.5f) * scale - 0.5f;
        int fp_ = (int)floorf(srcp), fq_ = (int)floorf(srcq);
        float tp = srcp - (float)fp_, tq = srcq - (float)fq_;
        float wp[4], wq[4];
        int ip[4], iq[4];
        #pragma unroll
        for (int k = 0; k < 4; ++k) {
            wp[k] = cubicw((float)(k - 1) - tp);
            wq[k] = cubicw((float)(k - 1) - tq);
            ip[k] = min(max(fp_ + k - 1, 0), pn - 1);
            iq[k] = min(max(fq_ + k - 1, 0), pn - 1);
        }
        for (int i = 0; i < 32; ++i) {
            float s = 0.f;
            #pragma unroll
            for (int kp = 0; kp < 4; ++kp) {
                float sr = 0.f;
                #pragma unroll
                for (int kq = 0; kq < 4; ++kq)
                    sr = fmaf(wq[kq], h_s[i][ip[kp] * pn + iq[kq]], sr);
                s = fmaf(wp[kp], sr, s);
            }
            hu_s[i][tid] = s;
        }
    }
    __syncthreads();

    // 4) conv 3x3 SAME over 32 in-ch for out-ch og..og+15
    float acc[16];
    #pragma unroll
    for (int o = 0; o < 16; ++o) acc[o] = bias[og + o];
    for (int i = 0; i < 32; ++i) {
        float v[9];
        #pragma unroll
        for (int dy = 0; dy < 3; ++dy)
            #pragma unroll
            for (int dx = 0; dx < 3; ++dx) {
                int pp = p + dy - 1, qq = q + dx - 1;
                bool in = (pp >= 0) & (pp < 16) & (qq >= 0) & (qq < 16);
                v[dy * 3 + dx] = in ? hu_s[i][pp * 16 + qq] : 0.f;
            }
        #pragma unroll
        for (int o = 0; o < 16; ++o) {
            const float* wp_ = w + ((og + o) * 32 + i) * 9;
            #pragma unroll
            for (int k = 0; k < 9; ++k) acc[o] = fmaf(wp_[k], v[k], acc[o]);
        }
    }

    // 5) blend + update f_hat/f_rest, stage new values into LDS (overlay on h_s)
    #pragma unroll
    for (int o = 0; o < 16; ++o) {
        int gi = (bb * 32 + og + o) * 256 + tid;
        float hu = hu_s[og + o][tid];
        float blend = 0.5f * hu + 0.5f * acc[o];
        float nf = f_hat[gi] + blend;
        float nr = f_rest[gi] - blend;
        f_hat[gi] = nf; f_rest[gi] = nr;
        fh_s[o][tid] = nf; fr_s[o][tid] = nr;
    }
    __syncthreads();

    // 6) context: area-pool new f_hat to pn x pn, write transposed slice of out [B,680,C]
    for (int e = tid; e < 16 * npx; e += 256) {
        int o = e & 15, n = e >> 4;
        int y = n / pn, x = n - y * pn;
        int sh = (y * HH) / pn, eh = ((y + 1) * HH + pn - 1) / pn;
        int sw = (x * HH) / pn, ew = ((x + 1) * HH + pn - 1) / pn;
        float s = 0.f;
        for (int yy = sh; yy < eh; ++yy)
            for (int xx = sw; xx < ew; ++xx) s += fh_s[o][yy * 16 + xx];
        out[((bb * 680) + off + n) * 32 + og + o] = s * (1.f / (float)((eh - sh) * (ew - sw)));
    }

    // 7) next-stage z: area-pool new f_rest to pn2 x pn2
    if (pn2 > 0) {
        int npx2 = pn2 * pn2;
        for (int e = tid; e < 16 * npx2; e += 256) {
            int o = e / npx2, n = e - o * npx2;
            int y = n / pn2, x = n - y * pn2;
            int sh = (y * HH) / pn2, eh = ((y + 1) * HH + pn2 - 1) / pn2;
            int sw = (x * HH) / pn2, ew = ((x + 1) * HH + pn2 - 1) / pn2;
            float s = 0.f;
            for (int yy = sh; yy < eh; ++yy)
                for (int xx = sw; xx < ew; ++xx) s += fr_s[o][yy * 16 + xx];
            znext[(bb * 32 + og + o) * npx2 + n] = s * (1.f / (float)((eh - sh) * (ew - sw)));
        }
    }
}

// ---------------- launch ----------------

extern "C" void kernel_launch(void* const* d_in, const int* in_sizes, int n_in,
                              void* d_out, int out_size, void* d_ws, size_t ws_size,
                              hipStream_t stream) {
    const float* feat = (const float*)d_in[0];
    const float* cb   = (const float*)d_in[1];
    const float* phiw = (const float*)d_in[2];
    const float* phib = (const float*)d_in[3];
    float* out = (float*)d_out;
    float* wsf = (float*)d_ws;

    const int NE = B * C * HH * HH; // 1048576
    float* f_rest = wsf;
    float* f_hat  = wsf + NE;
    float* zbuf   = wsf + 2 * NE;
    char*  tail   = (char*)(wsf + 3 * NE);
    double* c2d = (double*)tail;                        // 32 KB
    float*  c2f = (float*)(tail + (32 << 10));          // 16 KB
    float*  pb1 = (float*)(tail + (48 << 10));          // 3 MB each
    float*  pb2 = (float*)(tail + (48 << 10) + 3145728);
    int*    pi1 = (int*)  (tail + (48 << 10) + 2 * 3145728);

    static const int PN_[10]   = {1, 2, 3, 4, 5, 6, 8, 10, 13, 16};
    static const int PI_[10]   = {0, 0, 1, 1, 1, 2, 2, 2, 3, 3};
    static const int OFF_[10]  = {0, 1, 5, 14, 30, 55, 91, 155, 255, 424};
    static const int NSEG_[10] = {32, 32, 32, 32, 32, 16, 16, 8, 4, 4};

    init_kernel<<<dim3((NE + 255) / 256), dim3(256), 0, stream>>>(feat, f_rest, f_hat);
    c2_kernel<<<dim3(V / 256), dim3(256), 0, stream>>>(cb, c2d, c2f);
    area_down_kernel<<<dim3((B * C + 255) / 256), dim3(256), 0, stream>>>(f_rest, zbuf, 1);

    for (int si = 0; si < 10; ++si) {
        int pn = PN_[si], npx = pn * pn;
        int tokens = B * npx;          // always divisible by 64
        int nseg = NSEG_[si];
        int nblk_tok = tokens / TB;

        scan_gemm_kernel<<<dim3(nblk_tok * nseg), dim3(256), 0, stream>>>(
            zbuf, cb, c2f, pb1, pb2, pi1, npx, nseg, nblk_tok);

        int pn2 = (si < 9) ? PN_[si + 1] : 0;
        stage_tail_kernel<<<dim3(B * 2), dim3(256), 0, stream>>>(
            pb1, pb2, pi1, zbuf, cb, c2d,
            phiw + PI_[si] * C * C * 9, phib + PI_[si] * C,
            f_hat, f_rest, out, zbuf, pn, OFF_[si], pn2, nseg);
    }
}

// Round 11
// 1112.825 us; speedup vs baseline: 29.6930x; 1.0588x over previous
//
#include <hip/hip_runtime.h>

#define B 128
#define C 32
#define HH 16
#define V 4096
#define TB 64
#define CB 256
#define MARGIN 5e-4f

// ---------------- helpers ----------------

__device__ __forceinline__ float cubicw(float t) {
    float at = fabsf(t);
    float at2 = at * at, at3 = at2 * at;
    if (at <= 1.f) return 1.25f * at3 - 2.25f * at2 + 1.f;
    if (at < 2.f)  return -0.75f * at3 + 3.75f * at2 - 6.f * at + 3.f;
    return 0.f;
}

// ---------------- kernels ----------------

__global__ void init_kernel(const float* __restrict__ feat, float* __restrict__ f_rest,
                            float* __restrict__ f_hat) {
    int i = blockIdx.x * 256 + threadIdx.x;
    if (i < B * C * HH * HH) { f_rest[i] = feat[i]; f_hat[i] = 0.f; }
}

__global__ void c2_kernel(const float* __restrict__ cb, double* __restrict__ c2d,
                          float* __restrict__ c2f) {
    int v = blockIdx.x * 256 + threadIdx.x;
    if (v < V) {
        const float* p = cb + v * C;
        double s = 0.0;
        #pragma unroll
        for (int j = 0; j < C; ++j) { double d = (double)p[j]; s = fma(d, d, s); }
        c2d[v] = s;
        c2f[v] = (float)s;
    }
}

// area downsample for stage-0 z only (pn=1)
__global__ void area_down_kernel(const float* __restrict__ src, float* __restrict__ dst, int pn) {
    int i = blockIdx.x * blockDim.x + threadIdx.x;
    int npx = pn * pn;
    int total = B * C * npx;
    if (i >= total) return;
    int x = i % pn, y = (i / pn) % pn, bc = i / npx;
    int sh = (y * HH) / pn, eh = ((y + 1) * HH + pn - 1) / pn;
    int sw = (x * HH) / pn, ew = ((x + 1) * HH + pn - 1) / pn;
    const float* p = src + bc * (HH * HH);
    float s = 0.f;
    for (int yy = sh; yy < eh; ++yy)
        for (int xx = sw; xx < ew; ++xx) s += p[yy * HH + xx];
    dst[i] = s * (1.f / (float)((eh - sh) * (ew - sw)));
}

// ---- GEMM-tiled fp32 top-2 scan: 64 tok x 256 code tiles, thread = 8 tok x 8 codes ----
// 4 ds_read_b128 feed 64 FMA. unroll 1 + launch_bounds(256,3): keep the register
// window small (R8 spill lesson); acc[8][8] + b1/b2/i1[8] ~ 120 VGPR < 170 cap.
__global__ __launch_bounds__(256, 3) void scan_gemm_kernel(
    const float* __restrict__ z, const float* __restrict__ cb,
    const float* __restrict__ c2f, float* __restrict__ pb1,
    float* __restrict__ pb2, int* __restrict__ pi1,
    int npx, int nseg, int nblk_tok)
{
    int tid = threadIdx.x;
    int tb  = blockIdx.x % nblk_tok;
    int seg = blockIdx.x / nblk_tok;
    int cps = V / nseg;           // >= 256 always
    int sb  = seg * cps;
    int t0  = tb * TB;
    int total = B * npx;

    __shared__ float ldsZ[C][TB];
    __shared__ alignas(16) float ldsC[C][CB];
    __shared__ float lc2[CB];
    // merge arrays overlay ldsC (dead after last tile): 3 x [32][68] = 26.1 KB <= 32 KB
    float* mb1 = &ldsC[0][0];
    float* mb2 = mb1 + 32 * 68;
    int*   mi1 = (int*)(mb2 + 32 * 68);

    // stage z tile [32][64]
    #pragma unroll
    for (int i = 0; i < 8; ++i) {
        int e = tid + i * 256;
        int c = e >> 6, t = e & 63;
        int tok = t0 + t;
        int bq = tok / npx, n = tok - bq * npx;
        ldsZ[c][t] = z[(bq * C + c) * npx + n];
    }

    int cg = tid & 31, tg = tid >> 5;   // thread: tokens tg*8..+7, codes cg*8..+7

    float b1[8], b2[8]; int i1[8];
    #pragma unroll
    for (int i = 0; i < 8; ++i) { b1[i] = 3e38f; b2[i] = 3e38f; i1[i] = 0; }

    for (int tile = 0; tile < cps / CB; ++tile) {
        int code0 = sb + tile * CB;
        __syncthreads();
        // stage 256-code tile transposed: thread loads full row of code cc = tid
        {
            int cc = tid;
            const float4* cp = reinterpret_cast<const float4*>(cb + (size_t)(code0 + cc) * C);
            #pragma unroll
            for (int qq = 0; qq < 8; ++qq) {
                float4 q = cp[qq];
                ldsC[4 * qq + 0][cc] = q.x; ldsC[4 * qq + 1][cc] = q.y;
                ldsC[4 * qq + 2][cc] = q.z; ldsC[4 * qq + 3][cc] = q.w;
            }
            lc2[tid] = c2f[code0 + tid];
        }
        __syncthreads();

        float acc[8][8];
        #pragma unroll
        for (int i = 0; i < 8; ++i)
            #pragma unroll
            for (int j = 0; j < 8; ++j) acc[i][j] = 0.f;

        #pragma unroll 1
        for (int k = 0; k < C; ++k) {
            float4 z0 = *reinterpret_cast<const float4*>(&ldsZ[k][tg * 8]);
            float4 z1 = *reinterpret_cast<const float4*>(&ldsZ[k][tg * 8 + 4]);
            float4 c0 = *reinterpret_cast<const float4*>(&ldsC[k][cg * 8]);
            float4 c1 = *reinterpret_cast<const float4*>(&ldsC[k][cg * 8 + 4]);
#define FMAROW(ti, zc) \
            acc[ti][0] = fmaf(zc, c0.x, acc[ti][0]); acc[ti][1] = fmaf(zc, c0.y, acc[ti][1]); \
            acc[ti][2] = fmaf(zc, c0.z, acc[ti][2]); acc[ti][3] = fmaf(zc, c0.w, acc[ti][3]); \
            acc[ti][4] = fmaf(zc, c1.x, acc[ti][4]); acc[ti][5] = fmaf(zc, c1.y, acc[ti][5]); \
            acc[ti][6] = fmaf(zc, c1.z, acc[ti][6]); acc[ti][7] = fmaf(zc, c1.w, acc[ti][7]);
            FMAROW(0, z0.x) FMAROW(1, z0.y) FMAROW(2, z0.z) FMAROW(3, z0.w)
            FMAROW(4, z1.x) FMAROW(5, z1.y) FMAROW(6, z1.z) FMAROW(7, z1.w)
#undef FMAROW
        }

        // top-2 epilogue; ascending code order for ties (strict < keeps lowest idx)
        #pragma unroll
        for (int j = 0; j < 8; ++j) {
            int code = code0 + cg * 8 + j;
            float cc2 = lc2[cg * 8 + j];
            #pragma unroll
            for (int i = 0; i < 8; ++i) {
                float s = fmaf(-2.f, acc[i][j], cc2);
                if (s < b1[i]) { b2[i] = b1[i]; b1[i] = s; i1[i] = code; }
                else if (s < b2[i]) { b2[i] = s; }
            }
        }
    }

    __syncthreads();   // ldsC dead -> merge overlay
    #pragma unroll
    for (int i = 0; i < 8; ++i) {
        mb1[cg * 68 + tg * 8 + i] = b1[i];
        mb2[cg * 68 + tg * 8 + i] = b2[i];
        mi1[cg * 68 + tg * 8 + i] = i1[i];
    }
    __syncthreads();
    if (tid < TB) {
        float gb1 = 3e38f, gb2 = 3e38f; int gi1 = 0;
        #pragma unroll
        for (int g = 0; g < 32; ++g) {
            float v1 = mb1[g * 68 + tid]; int ix = mi1[g * 68 + tid];
            if (v1 < gb1 || (v1 == gb1 && ix < gi1)) { gb2 = gb1; gb1 = v1; gi1 = ix; }
            else if (v1 < gb2) { gb2 = v1; }
            float v2 = mb2[g * 68 + tid];
            if (v2 < gb2) gb2 = v2;
        }
        int tok = t0 + tid;
        pb1[(size_t)seg * total + tok] = gb1;
        pb2[(size_t)seg * total + tok] = gb2;
        pi1[(size_t)seg * total + tok] = gi1;
    }
}

// fused stage tail: combine+recheck -> gather -> bicubic -> conv3x3 (w in LDS)
//                   -> blend/update -> context pool -> next-z pool
__global__ __launch_bounds__(256) void stage_tail_kernel(
    const float* __restrict__ pb1, const float* __restrict__ pb2,
    const int* __restrict__ pi1, const float* __restrict__ z,
    const float* __restrict__ cb, const double* __restrict__ c2d,
    const float* __restrict__ w, const float* __restrict__ bias,
    float* __restrict__ f_hat, float* __restrict__ f_rest,
    float* __restrict__ out, float* __restrict__ znext,
    int pn, int off, int pn2, int nseg)
{
    int bb = blockIdx.x >> 1;
    int og = (blockIdx.x & 1) * 16;
    int tid = threadIdx.x;
    int npx = pn * pn;
    int total = B * npx;

    __shared__ float h_s[32][257];
    __shared__ float hu_s[32][257];
    __shared__ alignas(16) float w_s[16 * 384];  // [o][i][12] padded rows, 24 KB
    __shared__ int idx_s[256];
    __shared__ int flist[256];
    __shared__ int fcnt;
    __shared__ double zsd[C];
    __shared__ double sred[256];
    __shared__ int sidx[256];
    float (*fh_s)[257] = &h_s[0];
    float (*fr_s)[257] = &h_s[16];

    // -1) stage this block's w-half into LDS (coalesced; overlaps combine below).
    //     R10: 4608 scalar w-loads with dependent FMAs stalled the conv ~90%.
    for (int e = tid; e < 16 * 288; e += 256) {
        int o = e / 288, r = e - o * 288;      // r = i*9 + k
        w_s[o * 384 + (r / 9) * 12 + (r % 9)] = w[og * 288 + e];
    }

    // 0) combine per-segment top-2 -> idx or ambiguous flag
    if (tid == 0) fcnt = 0;
    __syncthreads();
    for (int n = tid; n < npx; n += 256) {
        int tok = bb * npx + n;
        float gb1 = 3e38f, gb2 = 3e38f; int gi1 = 0;
        for (int s = 0; s < nseg; ++s) {
            float v1 = pb1[(size_t)s * total + tok];
            if (v1 < gb1) { gb2 = gb1; gb1 = v1; gi1 = pi1[(size_t)s * total + tok]; }
            else if (v1 < gb2) { gb2 = v1; }
            float v2 = pb2[(size_t)s * total + tok];
            if (v2 < gb2) gb2 = v2;
        }
        idx_s[n] = gi1;
        if (gb2 - gb1 < MARGIN) { int slot = atomicAdd(&fcnt, 1); flist[slot] = n; }
    }
    __syncthreads();

    // 1) exact fp64 rescan for ambiguous tokens (block-parallel, rare)
    int nf = fcnt;
    for (int f = 0; f < nf; ++f) {
        int n = flist[f];
        if (tid < C) zsd[tid] = (double)z[(bb * C + tid) * npx + n];
        __syncthreads();
        double best = 1e300; int bi = 0x7fffffff;
        for (int k = 0; k < V / 256; ++k) {
            int v = tid + k * 256;
            const float4* cp = reinterpret_cast<const float4*>(cb + (size_t)v * C);
            double acc = 0.0;
            #pragma unroll
            for (int qq = 0; qq < 8; ++qq) {
                float4 fv = cp[qq];
                acc = fma((double)fv.x, zsd[4 * qq + 0], acc);
                acc = fma((double)fv.y, zsd[4 * qq + 1], acc);
                acc = fma((double)fv.z, zsd[4 * qq + 2], acc);
                acc = fma((double)fv.w, zsd[4 * qq + 3], acc);
            }
            double s = fma(-2.0, acc, c2d[v]);
            if (s < best || (s == best && v < bi)) { best = s; bi = v; }
        }
        sred[tid] = best; sidx[tid] = bi;
        __syncthreads();
        for (int st = 128; st > 0; st >>= 1) {
            if (tid < st) {
                double o = sred[tid + st]; int oi = sidx[tid + st];
                double me = sred[tid];     int mi = sidx[tid];
                if (o < me || (o == me && oi < mi)) { sred[tid] = o; sidx[tid] = oi; }
            }
            __syncthreads();
        }
        if (tid == 0) idx_s[n] = sidx[0];
        __syncthreads();
    }
    __syncthreads();

    // 2) gather hard embeddings h[c][n] = cb[idx[n]][c]
    for (int e = tid; e < 32 * npx; e += 256) {
        int c = e & 31, n = e >> 5;
        h_s[c][n] = cb[idx_s[n] * 32 + c];
    }
    __syncthreads();

    // 3) bicubic upsample pn x pn -> 16 x 16 (identity when pn==16)
    int p = tid >> 4, q = tid & 15;
    {
        float scale = (float)pn * (1.f / 16.f);
        float srcp = (p + 0.5f) * scale - 0.5f;
        float srcq = (q + 0.5f) * scale - 0.5f;
        int fp_ = (int)floorf(srcp), fq_ = (int)floorf(srcq);
        float tp = srcp - (float)fp_, tq = srcq - (float)fq_;
        float wp[4], wq[4];
        int ip[4], iq[4];
        #pragma unroll
        for (int k = 0; k < 4; ++k) {
            wp[k] = cubicw((float)(k - 1) - tp);
            wq[k] = cubicw((float)(k - 1) - tq);
            ip[k] = min(max(fp_ + k - 1, 0), pn - 1);
            iq[k] = min(max(fq_ + k - 1, 0), pn - 1);
        }
        for (int i = 0; i < 32; ++i) {
            float s = 0.f;
            #pragma unroll
            for (int kp = 0; kp < 4; ++kp) {
                float sr = 0.f;
                #pragma unroll
                for (int kq = 0; kq < 4; ++kq)
                    sr = fmaf(wq[kq], h_s[i][ip[kp] * pn + iq[kq]], sr);
                s = fmaf(wp[kp], sr, s);
            }
            hu_s[i][tid] = s;
        }
    }
    __syncthreads();

    // 4) conv 3x3 SAME over 32 in-ch for out-ch og..og+15; w via LDS broadcast
    float acc[16];
    #pragma unroll
    for (int o = 0; o < 16; ++o) acc[o] = bias[og + o];
    for (int i = 0; i < 32; ++i) {
        float v[9];
        #pragma unroll
        for (int dy = 0; dy < 3; ++dy)
            #pragma unroll
            for (int dx = 0; dx < 3; ++dx) {
                int pp = p + dy - 1, qq = q + dx - 1;
                bool in = (pp >= 0) & (pp < 16) & (qq >= 0) & (qq < 16);
                v[dy * 3 + dx] = in ? hu_s[i][pp * 16 + qq] : 0.f;
            }
        #pragma unroll
        for (int o = 0; o < 16; ++o) {
            const float* wr = &w_s[o * 384 + i * 12];
            float4 wa = *reinterpret_cast<const float4*>(wr);
            float4 wb = *reinterpret_cast<const float4*>(wr + 4);
            float w8 = wr[8];
            acc[o] = fmaf(wa.x, v[0], acc[o]); acc[o] = fmaf(wa.y, v[1], acc[o]);
            acc[o] = fmaf(wa.z, v[2], acc[o]); acc[o] = fmaf(wa.w, v[3], acc[o]);
            acc[o] = fmaf(wb.x, v[4], acc[o]); acc[o] = fmaf(wb.y, v[5], acc[o]);
            acc[o] = fmaf(wb.z, v[6], acc[o]); acc[o] = fmaf(wb.w, v[7], acc[o]);
            acc[o] = fmaf(w8,   v[8], acc[o]);
        }
    }

    // 5) blend + update f_hat/f_rest, stage new values into LDS (overlay on h_s)
    #pragma unroll
    for (int o = 0; o < 16; ++o) {
        int gi = (bb * 32 + og + o) * 256 + tid;
        float hu = hu_s[og + o][tid];
        float blend = 0.5f * hu + 0.5f * acc[o];
        float nf = f_hat[gi] + blend;
        float nr = f_rest[gi] - blend;
        f_hat[gi] = nf; f_rest[gi] = nr;
        fh_s[o][tid] = nf; fr_s[o][tid] = nr;
    }
    __syncthreads();

    // 6) context: area-pool new f_hat to pn x pn, write transposed slice of out [B,680,C]
    for (int e = tid; e < 16 * npx; e += 256) {
        int o = e & 15, n = e >> 4;
        int y = n / pn, x = n - y * pn;
        int sh = (y * HH) / pn, eh = ((y + 1) * HH + pn - 1) / pn;
        int sw = (x * HH) / pn, ew = ((x + 1) * HH + pn - 1) / pn;
        float s = 0.f;
        for (int yy = sh; yy < eh; ++yy)
            for (int xx = sw; xx < ew; ++xx) s += fh_s[o][yy * 16 + xx];
        out[((bb * 680) + off + n) * 32 + og + o] = s * (1.f / (float)((eh - sh) * (ew - sw)));
    }

    // 7) next-stage z: area-pool new f_rest to pn2 x pn2
    if (pn2 > 0) {
        int npx2 = pn2 * pn2;
        for (int e = tid; e < 16 * npx2; e += 256) {
            int o = e / npx2, n = e - o * npx2;
            int y = n / pn2, x = n - y * pn2;
            int sh = (y * HH) / pn2, eh = ((y + 1) * HH + pn2 - 1) / pn2;
            int sw = (x * HH) / pn2, ew = ((x + 1) * HH + pn2 - 1) / pn2;
            float s = 0.f;
            for (int yy = sh; yy < eh; ++yy)
                for (int xx = sw; xx < ew; ++xx) s += fr_s[o][yy * 16 + xx];
            znext[(bb * 32 + og + o) * npx2 + n] = s * (1.f / (float)((eh - sh) * (ew - sw)));
        }
    }
}

// ---------------- launch ----------------

extern "C" void kernel_launch(void* const* d_in, const int* in_sizes, int n_in,
                              void* d_out, int out_size, void* d_ws, size_t ws_size,
                              hipStream_t stream) {
    const float* feat = (const float*)d_in[0];
    const float* cb   = (const float*)d_in[1];
    const float* phiw = (const float*)d_in[2];
    const float* phib = (const float*)d_in[3];
    float* out = (float*)d_out;
    float* wsf = (float*)d_ws;

    const int NE = B * C * HH * HH; // 1048576
    float* f_rest = wsf;
    float* f_hat  = wsf + NE;
    float* zbuf   = wsf + 2 * NE;
    char*  tail   = (char*)(wsf + 3 * NE);
    double* c2d = (double*)tail;                        // 32 KB
    float*  c2f = (float*)(tail + (32 << 10));          // 16 KB
    float*  pb1 = (float*)(tail + (48 << 10));          // 3 MB each
    float*  pb2 = (float*)(tail + (48 << 10) + 3145728);
    int*    pi1 = (int*)  (tail + (48 << 10) + 2 * 3145728);

    static const int PN_[10]   = {1, 2, 3, 4, 5, 6, 8, 10, 13, 16};
    static const int PI_[10]   = {0, 0, 1, 1, 1, 2, 2, 2, 3, 3};
    static const int OFF_[10]  = {0, 1, 5, 14, 30, 55, 91, 155, 255, 424};
    static const int NSEG_[10] = {16, 16, 16, 16, 16, 16, 8, 8, 4, 4};

    init_kernel<<<dim3((NE + 255) / 256), dim3(256), 0, stream>>>(feat, f_rest, f_hat);
    c2_kernel<<<dim3(V / 256), dim3(256), 0, stream>>>(cb, c2d, c2f);
    area_down_kernel<<<dim3((B * C + 255) / 256), dim3(256), 0, stream>>>(f_rest, zbuf, 1);

    for (int si = 0; si < 10; ++si) {
        int pn = PN_[si], npx = pn * pn;
        int tokens = B * npx;          // always divisible by 64
        int nseg = NSEG_[si];
        int nblk_tok = tokens / TB;

        scan_gemm_kernel<<<dim3(nblk_tok * nseg), dim3(256), 0, stream>>>(
            zbuf, cb, c2f, pb1, pb2, pi1, npx, nseg, nblk_tok);

        int pn2 = (si < 9) ? PN_[si + 1] : 0;
        stage_tail_kernel<<<dim3(B * 2), dim3(256), 0, stream>>>(
            pb1, pb2, pi1, zbuf, cb, c2d,
            phiw + PI_[si] * C * C * 9, phib + PI_[si] * C,
            f_hat, f_rest, out, zbuf, pn, OFF_[si], pn2, nseg);
    }
}

// Round 12
// 1088.702 us; speedup vs baseline: 30.3510x; 1.0222x over previous
//
#include <hip/hip_runtime.h>

#define B 128
#define C 32
#define HH 16
#define V 4096
#define TB 64
#define CB 256
#define MARGIN 5e-4f

// ---------------- helpers ----------------

__device__ __forceinline__ float cubicw(float t) {
    float at = fabsf(t);
    float at2 = at * at, at3 = at2 * at;
    if (at <= 1.f) return 1.25f * at3 - 2.25f * at2 + 1.f;
    if (at < 2.f)  return -0.75f * at3 + 3.75f * at2 - 6.f * at + 3.f;
    return 0.f;
}

// ---------------- kernels ----------------

// fused setup: f_rest=feat, f_hat=0, c2 (fp64+fp32), stage-0 z (global mean)
__global__ void setup_kernel(const float* __restrict__ feat, float* __restrict__ f_rest,
                             float* __restrict__ f_hat, const float* __restrict__ cb,
                             double* __restrict__ c2d, float* __restrict__ c2f,
                             float* __restrict__ z0) {
    int i = blockIdx.x * 256 + threadIdx.x;
    if (i < B * C * HH * HH) { f_rest[i] = feat[i]; f_hat[i] = 0.f; }
    if (i < V) {
        const float* p = cb + i * C;
        double s = 0.0;
        #pragma unroll
        for (int j = 0; j < C; ++j) { double d = (double)p[j]; s = fma(d, d, s); }
        c2d[i] = s;
        c2f[i] = (float)s;
    }
    if (i < B * C) {
        const float* p = feat + i * (HH * HH);
        float s = 0.f;
        for (int px = 0; px < HH * HH; ++px) s += p[px];
        z0[i] = s * (1.f / 256.f);
    }
}

// ---- GEMM-tiled fp32 top-2 scan: 64 tok x 256 code tiles, thread = 8 tok x 8 codes ----
// Code ownership is b64-strided ({2cg+p+64j}): float2 reads at 8B lane stride ->
// 2-way bank access (free). R11's contiguous 8-code reads were ~8-way (12M conflicts).
__global__ __launch_bounds__(256, 3) void scan_gemm_kernel(
    const float* __restrict__ z, const float* __restrict__ cb,
    const float* __restrict__ c2f, float* __restrict__ pb1,
    float* __restrict__ pb2, int* __restrict__ pi1,
    int npx, int nseg, int nblk_tok)
{
    int tid = threadIdx.x;
    int tb  = blockIdx.x % nblk_tok;
    int seg = blockIdx.x / nblk_tok;
    int cps = V / nseg;           // >= 256 always
    int sb  = seg * cps;
    int t0  = tb * TB;
    int total = B * npx;

    __shared__ float ldsZ[C][TB];
    __shared__ alignas(16) float ldsC[C][CB];
    __shared__ float lc2[CB];
    // merge arrays overlay ldsC (dead after last tile): 3 x [32][68] = 26.1 KB
    float* mb1 = &ldsC[0][0];
    float* mb2 = mb1 + 32 * 68;
    int*   mi1 = (int*)(mb2 + 32 * 68);

    // stage z tile [32][64]
    #pragma unroll
    for (int i = 0; i < 8; ++i) {
        int e = tid + i * 256;
        int c = e >> 6, t = e & 63;
        int tok = t0 + t;
        int bq = tok / npx, n = tok - bq * npx;
        ldsZ[c][t] = z[(bq * C + c) * npx + n];
    }

    int cg = tid & 31, tg = tid >> 5;   // thread: tokens tg*8..+7, codes {2cg+p+64j}

    float b1[8], b2[8]; int i1[8];
    #pragma unroll
    for (int i = 0; i < 8; ++i) { b1[i] = 3e38f; b2[i] = 3e38f; i1[i] = 0; }

    for (int tile = 0; tile < cps / CB; ++tile) {
        int code0 = sb + tile * CB;
        __syncthreads();
        // stage 256-code tile transposed: thread loads full row of code cc = tid
        {
            int cc = tid;
            const float4* cp = reinterpret_cast<const float4*>(cb + (size_t)(code0 + cc) * C);
            #pragma unroll
            for (int qq = 0; qq < 8; ++qq) {
                float4 q = cp[qq];
                ldsC[4 * qq + 0][cc] = q.x; ldsC[4 * qq + 1][cc] = q.y;
                ldsC[4 * qq + 2][cc] = q.z; ldsC[4 * qq + 3][cc] = q.w;
            }
            lc2[tid] = c2f[code0 + tid];
        }
        __syncthreads();

        float acc[8][8];
        #pragma unroll
        for (int i = 0; i < 8; ++i)
            #pragma unroll
            for (int j = 0; j < 8; ++j) acc[i][j] = 0.f;

        #pragma unroll 1
        for (int k = 0; k < C; ++k) {
            float4 z0v = *reinterpret_cast<const float4*>(&ldsZ[k][tg * 8]);
            float4 z1v = *reinterpret_cast<const float4*>(&ldsZ[k][tg * 8 + 4]);
            float2 c0 = *reinterpret_cast<const float2*>(&ldsC[k][2 * cg]);
            float2 c1 = *reinterpret_cast<const float2*>(&ldsC[k][2 * cg + 64]);
            float2 c2v = *reinterpret_cast<const float2*>(&ldsC[k][2 * cg + 128]);
            float2 c3 = *reinterpret_cast<const float2*>(&ldsC[k][2 * cg + 192]);
#define FMAROW(ti, zc) \
            acc[ti][0] = fmaf(zc, c0.x, acc[ti][0]); acc[ti][1] = fmaf(zc, c0.y, acc[ti][1]); \
            acc[ti][2] = fmaf(zc, c1.x, acc[ti][2]); acc[ti][3] = fmaf(zc, c1.y, acc[ti][3]); \
            acc[ti][4] = fmaf(zc, c2v.x, acc[ti][4]); acc[ti][5] = fmaf(zc, c2v.y, acc[ti][5]); \
            acc[ti][6] = fmaf(zc, c3.x, acc[ti][6]); acc[ti][7] = fmaf(zc, c3.y, acc[ti][7]);
            FMAROW(0, z0v.x) FMAROW(1, z0v.y) FMAROW(2, z0v.z) FMAROW(3, z0v.w)
            FMAROW(4, z1v.x) FMAROW(5, z1v.y) FMAROW(6, z1v.z) FMAROW(7, z1v.w)
#undef FMAROW
        }

        // top-2 epilogue; per-thread code sequence ascending -> strict < keeps lowest idx
        #pragma unroll
        for (int j = 0; j < 8; ++j) {
            int col = 2 * cg + (j >> 1) * 64 + (j & 1);
            int code = code0 + col;
            float cc2 = lc2[col];
            #pragma unroll
            for (int i = 0; i < 8; ++i) {
                float s = fmaf(-2.f, acc[i][j], cc2);
                if (s < b1[i]) { b2[i] = b1[i]; b1[i] = s; i1[i] = code; }
                else if (s < b2[i]) { b2[i] = s; }
            }
        }
    }

    __syncthreads();   // ldsC dead -> merge overlay
    #pragma unroll
    for (int i = 0; i < 8; ++i) {
        mb1[cg * 68 + tg * 8 + i] = b1[i];
        mb2[cg * 68 + tg * 8 + i] = b2[i];
        mi1[cg * 68 + tg * 8 + i] = i1[i];
    }
    __syncthreads();
    if (tid < TB) {
        float gb1 = 3e38f, gb2 = 3e38f; int gi1 = 0;
        #pragma unroll
        for (int g = 0; g < 32; ++g) {
            float v1 = mb1[g * 68 + tid]; int ix = mi1[g * 68 + tid];
            if (v1 < gb1 || (v1 == gb1 && ix < gi1)) { gb2 = gb1; gb1 = v1; gi1 = ix; }
            else if (v1 < gb2) { gb2 = v1; }
            float v2 = mb2[g * 68 + tid];
            if (v2 < gb2) gb2 = v2;
        }
        int tok = t0 + tid;
        pb1[(size_t)seg * total + tok] = gb1;
        pb2[(size_t)seg * total + tok] = gb2;
        pi1[(size_t)seg * total + tok] = gi1;
    }
}

// fused stage tail: combine+recheck -> gather -> bicubic -> conv3x3 (w in LDS)
//                   -> blend/update -> context pool -> next-z pool
__global__ __launch_bounds__(256) void stage_tail_kernel(
    const float* __restrict__ pb1, const float* __restrict__ pb2,
    const int* __restrict__ pi1, const float* __restrict__ z,
    const float* __restrict__ cb, const double* __restrict__ c2d,
    const float* __restrict__ w, const float* __restrict__ bias,
    float* __restrict__ f_hat, float* __restrict__ f_rest,
    float* __restrict__ out, float* __restrict__ znext,
    int pn, int off, int pn2, int nseg)
{
    int bb = blockIdx.x >> 1;
    int og = (blockIdx.x & 1) * 16;
    int tid = threadIdx.x;
    int npx = pn * pn;
    int total = B * npx;

    __shared__ float h_s[32][257];
    __shared__ float hu_s[32][257];
    __shared__ alignas(16) float w_s[16 * 384];  // [o][i][12] padded rows, 24 KB
    __shared__ int idx_s[256];
    __shared__ int flist[256];
    __shared__ int fcnt;
    __shared__ double zsd[C];
    __shared__ double sred[256];
    __shared__ int sidx[256];
    float (*fh_s)[257] = &h_s[0];
    float (*fr_s)[257] = &h_s[16];

    // -1) stage this block's w-half into LDS (coalesced; overlaps combine below)
    for (int e = tid; e < 16 * 288; e += 256) {
        int o = e / 288, r = e - o * 288;      // r = i*9 + k
        w_s[o * 384 + (r / 9) * 12 + (r % 9)] = w[og * 288 + e];
    }

    // 0) combine per-segment top-2 -> idx or ambiguous flag
    if (tid == 0) fcnt = 0;
    __syncthreads();
    for (int n = tid; n < npx; n += 256) {
        int tok = bb * npx + n;
        float gb1 = 3e38f, gb2 = 3e38f; int gi1 = 0;
        for (int s = 0; s < nseg; ++s) {
            float v1 = pb1[(size_t)s * total + tok];
            if (v1 < gb1) { gb2 = gb1; gb1 = v1; gi1 = pi1[(size_t)s * total + tok]; }
            else if (v1 < gb2) { gb2 = v1; }
            float v2 = pb2[(size_t)s * total + tok];
            if (v2 < gb2) gb2 = v2;
        }
        idx_s[n] = gi1;
        if (gb2 - gb1 < MARGIN) { int slot = atomicAdd(&fcnt, 1); flist[slot] = n; }
    }
    __syncthreads();

    // 1) exact fp64 rescan for ambiguous tokens (block-parallel, rare)
    int nf = fcnt;
    for (int f = 0; f < nf; ++f) {
        int n = flist[f];
        if (tid < C) zsd[tid] = (double)z[(bb * C + tid) * npx + n];
        __syncthreads();
        double best = 1e300; int bi = 0x7fffffff;
        for (int k = 0; k < V / 256; ++k) {
            int v = tid + k * 256;
            const float4* cp = reinterpret_cast<const float4*>(cb + (size_t)v * C);
            double acc = 0.0;
            #pragma unroll
            for (int qq = 0; qq < 8; ++qq) {
                float4 fv = cp[qq];
                acc = fma((double)fv.x, zsd[4 * qq + 0], acc);
                acc = fma((double)fv.y, zsd[4 * qq + 1], acc);
                acc = fma((double)fv.z, zsd[4 * qq + 2], acc);
                acc = fma((double)fv.w, zsd[4 * qq + 3], acc);
            }
            double s = fma(-2.0, acc, c2d[v]);
            if (s < best || (s == best && v < bi)) { best = s; bi = v; }
        }
        sred[tid] = best; sidx[tid] = bi;
        __syncthreads();
        for (int st = 128; st > 0; st >>= 1) {
            if (tid < st) {
                double o = sred[tid + st]; int oi = sidx[tid + st];
                double me = sred[tid];     int mi = sidx[tid];
                if (o < me || (o == me && oi < mi)) { sred[tid] = o; sidx[tid] = oi; }
            }
            __syncthreads();
        }
        if (tid == 0) idx_s[n] = sidx[0];
        __syncthreads();
    }
    __syncthreads();

    // 2) gather hard embeddings h[c][n] = cb[idx[n]][c]
    for (int e = tid; e < 32 * npx; e += 256) {
        int c = e & 31, n = e >> 5;
        h_s[c][n] = cb[idx_s[n] * 32 + c];
    }
    __syncthreads();

    // 3) bicubic upsample pn x pn -> 16 x 16 (identity when pn==16)
    int p = tid >> 4, q = tid & 15;
    {
        float scale = (float)pn * (1.f / 16.f);
        float srcp = (p + 0.5f) * scale - 0.5f;
        float srcq = (q + 0.5f) * scale - 0.5f;
        int fp_ = (int)floorf(srcp), fq_ = (int)floorf(srcq);
        float tp = srcp - (float)fp_, tq = srcq - (float)fq_;
        float wp[4], wq[4];
        int ip[4], iq[4];
        #pragma unroll
        for (int k = 0; k < 4; ++k) {
            wp[k] = cubicw((float)(k - 1) - tp);
            wq[k] = cubicw((float)(k - 1) - tq);
            ip[k] = min(max(fp_ + k - 1, 0), pn - 1);
            iq[k] = min(max(fq_ + k - 1, 0), pn - 1);
        }
        for (int i = 0; i < 32; ++i) {
            float s = 0.f;
            #pragma unroll
            for (int kp = 0; kp < 4; ++kp) {
                float sr = 0.f;
                #pragma unroll
                for (int kq = 0; kq < 4; ++kq)
                    sr = fmaf(wq[kq], h_s[i][ip[kp] * pn + iq[kq]], sr);
                s = fmaf(wp[kp], sr, s);
            }
            hu_s[i][tid] = s;
        }
    }
    __syncthreads();

    // 4) conv 3x3 SAME over 32 in-ch for out-ch og..og+15; w via LDS broadcast
    float acc[16];
    #pragma unroll
    for (int o = 0; o < 16; ++o) acc[o] = bias[og + o];
    for (int i = 0; i < 32; ++i) {
        float v[9];
        #pragma unroll
        for (int dy = 0; dy < 3; ++dy)
            #pragma unroll
            for (int dx = 0; dx < 3; ++dx) {
                int pp = p + dy - 1, qq = q + dx - 1;
                bool in = (pp >= 0) & (pp < 16) & (qq >= 0) & (qq < 16);
                v[dy * 3 + dx] = in ? hu_s[i][pp * 16 + qq] : 0.f;
            }
        #pragma unroll
        for (int o = 0; o < 16; ++o) {
            const float* wr = &w_s[o * 384 + i * 12];
            float4 wa = *reinterpret_cast<const float4*>(wr);
            float4 wb = *reinterpret_cast<const float4*>(wr + 4);
            float w8 = wr[8];
            acc[o] = fmaf(wa.x, v[0], acc[o]); acc[o] = fmaf(wa.y, v[1], acc[o]);
            acc[o] = fmaf(wa.z, v[2], acc[o]); acc[o] = fmaf(wa.w, v[3], acc[o]);
            acc[o] = fmaf(wb.x, v[4], acc[o]); acc[o] = fmaf(wb.y, v[5], acc[o]);
            acc[o] = fmaf(wb.z, v[6], acc[o]); acc[o] = fmaf(wb.w, v[7], acc[o]);
            acc[o] = fmaf(w8,   v[8], acc[o]);
        }
    }

    // 5) blend + update f_hat/f_rest, stage new values into LDS (overlay on h_s)
    #pragma unroll
    for (int o = 0; o < 16; ++o) {
        int gi = (bb * 32 + og + o) * 256 + tid;
        float hu = hu_s[og + o][tid];
        float blend = 0.5f * hu + 0.5f * acc[o];
        float nf = f_hat[gi] + blend;
        float nr = f_rest[gi] - blend;
        f_hat[gi] = nf; f_rest[gi] = nr;
        fh_s[o][tid] = nf; fr_s[o][tid] = nr;
    }
    __syncthreads();

    // 6) context: area-pool new f_hat to pn x pn, write transposed slice of out [B,680,C]
    for (int e = tid; e < 16 * npx; e += 256) {
        int o = e & 15, n = e >> 4;
        int y = n / pn, x = n - y * pn;
        int sh = (y * HH) / pn, eh = ((y + 1) * HH + pn - 1) / pn;
        int sw = (x * HH) / pn, ew = ((x + 1) * HH + pn - 1) / pn;
        float s = 0.f;
        for (int yy = sh; yy < eh; ++yy)
            for (int xx = sw; xx < ew; ++xx) s += fh_s[o][yy * 16 + xx];
        out[((bb * 680) + off + n) * 32 + og + o] = s * (1.f / (float)((eh - sh) * (ew - sw)));
    }

    // 7) next-stage z: area-pool new f_rest to pn2 x pn2
    if (pn2 > 0) {
        int npx2 = pn2 * pn2;
        for (int e = tid; e < 16 * npx2; e += 256) {
            int o = e / npx2, n = e - o * npx2;
            int y = n / pn2, x = n - y * pn2;
            int sh = (y * HH) / pn2, eh = ((y + 1) * HH + pn2 - 1) / pn2;
            int sw = (x * HH) / pn2, ew = ((x + 1) * HH + pn2 - 1) / pn2;
            float s = 0.f;
            for (int yy = sh; yy < eh; ++yy)
                for (int xx = sw; xx < ew; ++xx) s += fr_s[o][yy * 16 + xx];
            znext[(bb * 32 + og + o) * npx2 + n] = s * (1.f / (float)((eh - sh) * (ew - sw)));
        }
    }
}

// ---------------- launch ----------------

extern "C" void kernel_launch(void* const* d_in, const int* in_sizes, int n_in,
                              void* d_out, int out_size, void* d_ws, size_t ws_size,
                              hipStream_t stream) {
    const float* feat = (const float*)d_in[0];
    const float* cb   = (const float*)d_in[1];
    const float* phiw = (const float*)d_in[2];
    const float* phib = (const float*)d_in[3];
    float* out = (float*)d_out;
    float* wsf = (float*)d_ws;

    const int NE = B * C * HH * HH; // 1048576
    float* f_rest = wsf;
    float* f_hat  = wsf + NE;
    float* zbuf   = wsf + 2 * NE;
    char*  tail   = (char*)(wsf + 3 * NE);
    double* c2d = (double*)tail;                        // 32 KB
    float*  c2f = (float*)(tail + (32 << 10));          // 16 KB
    float*  pb1 = (float*)(tail + (48 << 10));          // 3 MB each
    float*  pb2 = (float*)(tail + (48 << 10) + 3145728);
    int*    pi1 = (int*)  (tail + (48 << 10) + 2 * 3145728);

    static const int PN_[10]   = {1, 2, 3, 4, 5, 6, 8, 10, 13, 16};
    static const int PI_[10]   = {0, 0, 1, 1, 1, 2, 2, 2, 3, 3};
    static const int OFF_[10]  = {0, 1, 5, 14, 30, 55, 91, 155, 255, 424};
    static const int NSEG_[10] = {16, 16, 16, 16, 16, 16, 8, 8, 4, 4};

    setup_kernel<<<dim3((NE + 255) / 256), dim3(256), 0, stream>>>(
        feat, f_rest, f_hat, cb, c2d, c2f, zbuf);

    for (int si = 0; si < 10; ++si) {
        int pn = PN_[si], npx = pn * pn;
        int tokens = B * npx;          // always divisible by 64
        int nseg = NSEG_[si];
        int nblk_tok = tokens / TB;

        scan_gemm_kernel<<<dim3(nblk_tok * nseg), dim3(256), 0, stream>>>(
            zbuf, cb, c2f, pb1, pb2, pi1, npx, nseg, nblk_tok);

        int pn2 = (si < 9) ? PN_[si + 1] : 0;
        stage_tail_kernel<<<dim3(B * 2), dim3(256), 0, stream>>>(
            pb1, pb2, pi1, zbuf, cb, c2d,
            phiw + PI_[si] * C * C * 9, phib + PI_[si] * C,
            f_hat, f_rest, out, zbuf, pn, OFF_[si], pn2, nseg);
    }
}

// Round 13
// 925.415 us; speedup vs baseline: 35.7063x; 1.1764x over previous
//
#include <hip/hip_runtime.h>

#define B 128
#define C 32
#define HH 16
#define V 4096
#define TB 64
#define CB 256
#define MARGIN 5e-4f

// ---------------- helpers ----------------

__device__ __forceinline__ float cubicw(float t) {
    float at = fabsf(t);
    float at2 = at * at, at3 = at2 * at;
    if (at <= 1.f) return 1.25f * at3 - 2.25f * at2 + 1.f;
    if (at < 2.f)  return -0.75f * at3 + 3.75f * at2 - 6.f * at + 3.f;
    return 0.f;
}

// ---------------- kernels ----------------

// fused setup: f_rest=feat, f_hat=0, c2 (fp64+fp32), stage-0 z (global mean)
__global__ void setup_kernel(const float* __restrict__ feat, float* __restrict__ f_rest,
                             float* __restrict__ f_hat, const float* __restrict__ cb,
                             double* __restrict__ c2d, float* __restrict__ c2f,
                             float* __restrict__ z0) {
    int i = blockIdx.x * 256 + threadIdx.x;
    if (i < B * C * HH * HH) { f_rest[i] = feat[i]; f_hat[i] = 0.f; }
    if (i < V) {
        const float* p = cb + i * C;
        double s = 0.0;
        #pragma unroll
        for (int j = 0; j < C; ++j) { double d = (double)p[j]; s = fma(d, d, s); }
        c2d[i] = s;
        c2f[i] = (float)s;
    }
    if (i < B * C) {
        const float* p = feat + i * (HH * HH);
        float s = 0.f;
        for (int px = 0; px < HH * HH; ++px) s += p[px];
        z0[i] = s * (1.f / 256.f);
    }
}

// ---- GEMM-tiled fp32 top-2 scan: 64 tok x 256 code tiles, thread = 8 tok x 8 codes ----
// LDS exactly 40 KB (no lc2 array -> c2 in registers, loaded from L2 under the
// k-loop) => 4 blocks/CU resident (R12: 41984 B capped us at ~2, Occ 27%).
__global__ __launch_bounds__(256, 4) void scan_gemm_kernel(
    const float* __restrict__ z, const float* __restrict__ cb,
    const float* __restrict__ c2f, float* __restrict__ pb1,
    float* __restrict__ pb2, int* __restrict__ pi1,
    int npx, int nseg, int nblk_tok)
{
    int tid = threadIdx.x;
    int tb  = blockIdx.x % nblk_tok;
    int seg = blockIdx.x / nblk_tok;
    int cps = V / nseg;           // >= 256 always
    int sb  = seg * cps;
    int t0  = tb * TB;
    int total = B * npx;

    __shared__ float ldsZ[C][TB];
    __shared__ alignas(16) float ldsC[C][CB];
    // merge arrays overlay ldsC (dead after last tile): 3 x [32][68] = 26.1 KB
    float* mb1 = &ldsC[0][0];
    float* mb2 = mb1 + 32 * 68;
    int*   mi1 = (int*)(mb2 + 32 * 68);

    // stage z tile [32][64]
    #pragma unroll
    for (int i = 0; i < 8; ++i) {
        int e = tid + i * 256;
        int c = e >> 6, t = e & 63;
        int tok = t0 + t;
        int bq = tok / npx, n = tok - bq * npx;
        ldsZ[c][t] = z[(bq * C + c) * npx + n];
    }

    int cg = tid & 31, tg = tid >> 5;   // thread: tokens tg*8..+7, codes {2cg+p+64j}

    float b1[8], b2[8]; int i1[8];
    #pragma unroll
    for (int i = 0; i < 8; ++i) { b1[i] = 3e38f; b2[i] = 3e38f; i1[i] = 0; }

    for (int tile = 0; tile < cps / CB; ++tile) {
        int code0 = sb + tile * CB;
        __syncthreads();
        // stage 256-code tile transposed: thread loads full row of code cc = tid
        {
            int cc = tid;
            const float4* cp = reinterpret_cast<const float4*>(cb + (size_t)(code0 + cc) * C);
            #pragma unroll
            for (int qq = 0; qq < 8; ++qq) {
                float4 q = cp[qq];
                ldsC[4 * qq + 0][cc] = q.x; ldsC[4 * qq + 1][cc] = q.y;
                ldsC[4 * qq + 2][cc] = q.z; ldsC[4 * qq + 3][cc] = q.w;
            }
        }
        // c2 for this thread's 8 codes -> registers (L2-hit, consumed after k-loop)
        float2 r01 = *reinterpret_cast<const float2*>(&c2f[code0 + 2 * cg]);
        float2 r23 = *reinterpret_cast<const float2*>(&c2f[code0 + 2 * cg + 64]);
        float2 r45 = *reinterpret_cast<const float2*>(&c2f[code0 + 2 * cg + 128]);
        float2 r67 = *reinterpret_cast<const float2*>(&c2f[code0 + 2 * cg + 192]);
        __syncthreads();

        float acc[8][8];
        #pragma unroll
        for (int i = 0; i < 8; ++i)
            #pragma unroll
            for (int j = 0; j < 8; ++j) acc[i][j] = 0.f;

        #pragma unroll 1
        for (int k = 0; k < C; ++k) {
            float4 z0v = *reinterpret_cast<const float4*>(&ldsZ[k][tg * 8]);
            float4 z1v = *reinterpret_cast<const float4*>(&ldsZ[k][tg * 8 + 4]);
            float2 c0 = *reinterpret_cast<const float2*>(&ldsC[k][2 * cg]);
            float2 c1 = *reinterpret_cast<const float2*>(&ldsC[k][2 * cg + 64]);
            float2 c2v = *reinterpret_cast<const float2*>(&ldsC[k][2 * cg + 128]);
            float2 c3 = *reinterpret_cast<const float2*>(&ldsC[k][2 * cg + 192]);
#define FMAROW(ti, zc) \
            acc[ti][0] = fmaf(zc, c0.x, acc[ti][0]); acc[ti][1] = fmaf(zc, c0.y, acc[ti][1]); \
            acc[ti][2] = fmaf(zc, c1.x, acc[ti][2]); acc[ti][3] = fmaf(zc, c1.y, acc[ti][3]); \
            acc[ti][4] = fmaf(zc, c2v.x, acc[ti][4]); acc[ti][5] = fmaf(zc, c2v.y, acc[ti][5]); \
            acc[ti][6] = fmaf(zc, c3.x, acc[ti][6]); acc[ti][7] = fmaf(zc, c3.y, acc[ti][7]);
            FMAROW(0, z0v.x) FMAROW(1, z0v.y) FMAROW(2, z0v.z) FMAROW(3, z0v.w)
            FMAROW(4, z1v.x) FMAROW(5, z1v.y) FMAROW(6, z1v.z) FMAROW(7, z1v.w)
#undef FMAROW
        }

        float rc2[8] = {r01.x, r01.y, r23.x, r23.y, r45.x, r45.y, r67.x, r67.y};
        // top-2 epilogue; per-thread code sequence ascending -> strict < keeps lowest idx
        #pragma unroll
        for (int j = 0; j < 8; ++j) {
            int code = code0 + 2 * cg + (j >> 1) * 64 + (j & 1);
            float cc2 = rc2[j];
            #pragma unroll
            for (int i = 0; i < 8; ++i) {
                float s = fmaf(-2.f, acc[i][j], cc2);
                if (s < b1[i]) { b2[i] = b1[i]; b1[i] = s; i1[i] = code; }
                else if (s < b2[i]) { b2[i] = s; }
            }
        }
    }

    __syncthreads();   // ldsC dead -> merge overlay
    #pragma unroll
    for (int i = 0; i < 8; ++i) {
        mb1[cg * 68 + tg * 8 + i] = b1[i];
        mb2[cg * 68 + tg * 8 + i] = b2[i];
        mi1[cg * 68 + tg * 8 + i] = i1[i];
    }
    __syncthreads();
    if (tid < TB) {
        float gb1 = 3e38f, gb2 = 3e38f; int gi1 = 0;
        #pragma unroll
        for (int g = 0; g < 32; ++g) {
            float v1 = mb1[g * 68 + tid]; int ix = mi1[g * 68 + tid];
            if (v1 < gb1 || (v1 == gb1 && ix < gi1)) { gb2 = gb1; gb1 = v1; gi1 = ix; }
            else if (v1 < gb2) { gb2 = v1; }
            float v2 = mb2[g * 68 + tid];
            if (v2 < gb2) gb2 = v2;
        }
        int tok = t0 + tid;
        pb1[(size_t)seg * total + tok] = gb1;
        pb2[(size_t)seg * total + tok] = gb2;
        pi1[(size_t)seg * total + tok] = gi1;
    }
}

// fused stage tail: B*4 blocks, 8 out-channels each (2 blocks/CU vs R12's 1 ->
// latency overlap; R10/R11 showed conv w-loads are NOT the stall, so w stays global).
__global__ __launch_bounds__(256) void stage_tail_kernel(
    const float* __restrict__ pb1, const float* __restrict__ pb2,
    const int* __restrict__ pi1, const float* __restrict__ z,
    const float* __restrict__ cb, const double* __restrict__ c2d,
    const float* __restrict__ w, const float* __restrict__ bias,
    float* __restrict__ f_hat, float* __restrict__ f_rest,
    float* __restrict__ out, float* __restrict__ znext,
    int pn, int off, int pn2, int nseg)
{
    int bb = blockIdx.x >> 2;
    int og = (blockIdx.x & 3) * 8;
    int tid = threadIdx.x;
    int npx = pn * pn;
    int total = B * npx;

    __shared__ float h_s[32][257];
    __shared__ float hu_s[32][257];
    __shared__ int idx_s[256];
    __shared__ int flist[256];
    __shared__ int fcnt;
    __shared__ double zsd[C];
    __shared__ double sred[256];
    __shared__ int sidx[256];
    float (*fh_s)[257] = &h_s[0];   // overlay: h_s rows 0..7 after gather is dead
    float (*fr_s)[257] = &h_s[8];

    // prefetch this block's f_hat/f_rest values (latency hides under combine..conv)
    float pf[8], pr[8];
    #pragma unroll
    for (int o = 0; o < 8; ++o) {
        int gi = (bb * 32 + og + o) * 256 + tid;
        pf[o] = f_hat[gi];
        pr[o] = f_rest[gi];
    }

    // 0) combine per-segment top-2 -> idx or ambiguous flag
    if (tid == 0) fcnt = 0;
    __syncthreads();
    for (int n = tid; n < npx; n += 256) {
        int tok = bb * npx + n;
        float gb1 = 3e38f, gb2 = 3e38f; int gi1 = 0;
        for (int s = 0; s < nseg; ++s) {
            float v1 = pb1[(size_t)s * total + tok];
            if (v1 < gb1) { gb2 = gb1; gb1 = v1; gi1 = pi1[(size_t)s * total + tok]; }
            else if (v1 < gb2) { gb2 = v1; }
            float v2 = pb2[(size_t)s * total + tok];
            if (v2 < gb2) gb2 = v2;
        }
        idx_s[n] = gi1;
        if (gb2 - gb1 < MARGIN) { int slot = atomicAdd(&fcnt, 1); flist[slot] = n; }
    }
    __syncthreads();

    // 1) exact fp64 rescan for ambiguous tokens (block-parallel, rare)
    int nf = fcnt;
    for (int f = 0; f < nf; ++f) {
        int n = flist[f];
        if (tid < C) zsd[tid] = (double)z[(bb * C + tid) * npx + n];
        __syncthreads();
        double best = 1e300; int bi = 0x7fffffff;
        for (int k = 0; k < V / 256; ++k) {
            int v = tid + k * 256;
            const float4* cp = reinterpret_cast<const float4*>(cb + (size_t)v * C);
            double acc = 0.0;
            #pragma unroll
            for (int qq = 0; qq < 8; ++qq) {
                float4 fv = cp[qq];
                acc = fma((double)fv.x, zsd[4 * qq + 0], acc);
                acc = fma((double)fv.y, zsd[4 * qq + 1], acc);
                acc = fma((double)fv.z, zsd[4 * qq + 2], acc);
                acc = fma((double)fv.w, zsd[4 * qq + 3], acc);
            }
            double s = fma(-2.0, acc, c2d[v]);
            if (s < best || (s == best && v < bi)) { best = s; bi = v; }
        }
        sred[tid] = best; sidx[tid] = bi;
        __syncthreads();
        for (int st = 128; st > 0; st >>= 1) {
            if (tid < st) {
                double o = sred[tid + st]; int oi = sidx[tid + st];
                double me = sred[tid];     int mi = sidx[tid];
                if (o < me || (o == me && oi < mi)) { sred[tid] = o; sidx[tid] = oi; }
            }
            __syncthreads();
        }
        if (tid == 0) idx_s[n] = sidx[0];
        __syncthreads();
    }
    __syncthreads();

    // 2) gather hard embeddings h[c][n] = cb[idx[n]][c]
    for (int e = tid; e < 32 * npx; e += 256) {
        int c = e & 31, n = e >> 5;
        h_s[c][n] = cb[idx_s[n] * 32 + c];
    }
    __syncthreads();

    // 3) bicubic upsample pn x pn -> 16 x 16 (identity when pn==16); all 32 in-ch
    int p = tid >> 4, q = tid & 15;
    {
        float scale = (float)pn * (1.f / 16.f);
        float srcp = (p + 0.5f) * scale - 0.5f;
        float srcq = (q + 0.5f) * scale - 0.5f;
        int fp_ = (int)floorf(srcp), fq_ = (int)floorf(srcq);
        float tp = srcp - (float)fp_, tq = srcq - (float)fq_;
        float wp[4], wq[4];
        int ip[4], iq[4];
        #pragma unroll
        for (int k = 0; k < 4; ++k) {
            wp[k] = cubicw((float)(k - 1) - tp);
            wq[k] = cubicw((float)(k - 1) - tq);
            ip[k] = min(max(fp_ + k - 1, 0), pn - 1);
            iq[k] = min(max(fq_ + k - 1, 0), pn - 1);
        }
        for (int i = 0; i < 32; ++i) {
            float s = 0.f;
            #pragma unroll
            for (int kp = 0; kp < 4; ++kp) {
                float sr = 0.f;
                #pragma unroll
                for (int kq = 0; kq < 4; ++kq)
                    sr = fmaf(wq[kq], h_s[i][ip[kp] * pn + iq[kq]], sr);
                s = fmaf(wp[kp], sr, s);
            }
            hu_s[i][tid] = s;
        }
    }
    __syncthreads();

    // 4) conv 3x3 SAME over 32 in-ch for out-ch og..og+7 (w wave-uniform -> scalar loads)
    float acc[8];
    #pragma unroll
    for (int o = 0; o < 8; ++o) acc[o] = bias[og + o];
    for (int i = 0; i < 32; ++i) {
        float v[9];
        #pragma unroll
        for (int dy = 0; dy < 3; ++dy)
            #pragma unroll
            for (int dx = 0; dx < 3; ++dx) {
                int pp = p + dy - 1, qq = q + dx - 1;
                bool in = (pp >= 0) & (pp < 16) & (qq >= 0) & (qq < 16);
                v[dy * 3 + dx] = in ? hu_s[i][pp * 16 + qq] : 0.f;
            }
        #pragma unroll
        for (int o = 0; o < 8; ++o) {
            const float* wp_ = w + ((og + o) * 32 + i) * 9;
            #pragma unroll
            for (int k = 0; k < 9; ++k) acc[o] = fmaf(wp_[k], v[k], acc[o]);
        }
    }

    // 5) blend + update f_hat/f_rest (prefetched), stage new values into LDS overlay
    #pragma unroll
    for (int o = 0; o < 8; ++o) {
        int gi = (bb * 32 + og + o) * 256 + tid;
        float hu = hu_s[og + o][tid];
        float blend = 0.5f * hu + 0.5f * acc[o];
        float nf = pf[o] + blend;
        float nr = pr[o] - blend;
        f_hat[gi] = nf; f_rest[gi] = nr;
        fh_s[o][tid] = nf; fr_s[o][tid] = nr;
    }
    __syncthreads();

    // 6) context: area-pool new f_hat to pn x pn, write transposed slice of out [B,680,C]
    for (int e = tid; e < 8 * npx; e += 256) {
        int o = e & 7, n = e >> 3;
        int y = n / pn, x = n - y * pn;
        int sh = (y * HH) / pn, eh = ((y + 1) * HH + pn - 1) / pn;
        int sw = (x * HH) / pn, ew = ((x + 1) * HH + pn - 1) / pn;
        float s = 0.f;
        for (int yy = sh; yy < eh; ++yy)
            for (int xx = sw; xx < ew; ++xx) s += fh_s[o][yy * 16 + xx];
        out[((bb * 680) + off + n) * 32 + og + o] = s * (1.f / (float)((eh - sh) * (ew - sw)));
    }

    // 7) next-stage z: area-pool new f_rest to pn2 x pn2 (separate buffer: no race)
    if (pn2 > 0) {
        int npx2 = pn2 * pn2;
        for (int e = tid; e < 8 * npx2; e += 256) {
            int o = e / npx2, n = e - o * npx2;
            int y = n / pn2, x = n - y * pn2;
            int sh = (y * HH) / pn2, eh = ((y + 1) * HH + pn2 - 1) / pn2;
            int sw = (x * HH) / pn2, ew = ((x + 1) * HH + pn2 - 1) / pn2;
            float s = 0.f;
            for (int yy = sh; yy < eh; ++yy)
                for (int xx = sw; xx < ew; ++xx) s += fr_s[o][yy * 16 + xx];
            znext[(bb * 32 + og + o) * npx2 + n] = s * (1.f / (float)((eh - sh) * (ew - sw)));
        }
    }
}

// ---------------- launch ----------------

extern "C" void kernel_launch(void* const* d_in, const int* in_sizes, int n_in,
                              void* d_out, int out_size, void* d_ws, size_t ws_size,
                              hipStream_t stream) {
    const float* feat = (const float*)d_in[0];
    const float* cb   = (const float*)d_in[1];
    const float* phiw = (const float*)d_in[2];
    const float* phib = (const float*)d_in[3];
    float* out = (float*)d_out;
    float* wsf = (float*)d_ws;

    const int NE = B * C * HH * HH; // 1048576
    float* f_rest = wsf;
    float* f_hat  = wsf + NE;
    float* zA     = wsf + 2 * NE;   // ping-pong z buffers (fixes z/znext overlap race)
    float* zB     = wsf + 3 * NE;
    char*  tail   = (char*)(wsf + 4 * NE);
    double* c2d = (double*)tail;                        // 32 KB
    float*  c2f = (float*)(tail + (32 << 10));          // 16 KB
    float*  pb1 = (float*)(tail + (48 << 10));          // 3 MB each
    float*  pb2 = (float*)(tail + (48 << 10) + 3145728);
    int*    pi1 = (int*)  (tail + (48 << 10) + 2 * 3145728);

    static const int PN_[10]   = {1, 2, 3, 4, 5, 6, 8, 10, 13, 16};
    static const int PI_[10]   = {0, 0, 1, 1, 1, 2, 2, 2, 3, 3};
    static const int OFF_[10]  = {0, 1, 5, 14, 30, 55, 91, 155, 255, 424};
    static const int NSEG_[10] = {16, 16, 16, 16, 16, 16, 8, 8, 4, 4};

    setup_kernel<<<dim3((NE + 255) / 256), dim3(256), 0, stream>>>(
        feat, f_rest, f_hat, cb, c2d, c2f, zA);

    for (int si = 0; si < 10; ++si) {
        int pn = PN_[si], npx = pn * pn;
        int tokens = B * npx;          // always divisible by 64
        int nseg = NSEG_[si];
        int nblk_tok = tokens / TB;
        float* zin  = (si & 1) ? zB : zA;
        float* zout = (si & 1) ? zA : zB;

        scan_gemm_kernel<<<dim3(nblk_tok * nseg), dim3(256), 0, stream>>>(
            zin, cb, c2f, pb1, pb2, pi1, npx, nseg, nblk_tok);

        int pn2 = (si < 9) ? PN_[si + 1] : 0;
        stage_tail_kernel<<<dim3(B * 4), dim3(256), 0, stream>>>(
            pb1, pb2, pi1, zin, cb, c2d,
            phiw + PI_[si] * C * C * 9, phib + PI_[si] * C,
            f_hat, f_rest, out, zout, pn, OFF_[si], pn2, nseg);
    }
}